// Round 15
// baseline (634.587 us; speedup 1.0000x reference)
//
#include <hip/hip_runtime.h>
#include <hip/hip_bf16.h>

#define DM 48
#define NS 21
#define HDm 24
#define ITERS 3
#define NWAVE 12   // 768 thr = 12 waves = 3/SIMD: proven no-spill point (84 VGPR cap)
#define NTHR (NWAVE*64)

#define KV_ST 60   // kvn/K row stride (u16): 30 dw, gcd(30,32)=2 -> bank period 16:
                   // scores reads ~2-way (free). Rows 8B-aligned -> frag loads = 2xb64.
#define VT_ST 28   // V^T row stride (u16): 14 dw -> period 16
#define UN_SZ 1344 // max(NS*KV_ST=1260, 48*VT_ST=1344)
#define WKV_ST 56  // wkv rows; col48 = bias, 49-55 = 0 (16B-aligned, b128 A-loads)
#define WQ_ST 56
#define WHN_ST 56
#define WC_ST 104  // W_cat = [wih@opw | whh] rows
#define P_ST 52

typedef short s16x8 __attribute__((ext_vector_type(8)));
typedef short s16x4 __attribute__((ext_vector_type(4)));
typedef float f32x4 __attribute__((ext_vector_type(4)));
typedef unsigned short u16;

__device__ __forceinline__ u16 f2bu(float f) {
    __hip_bfloat16 h = __float2bfloat16(f);
    return *reinterpret_cast<u16*>(&h);
}
__device__ __forceinline__ float bu2f_lo(unsigned u){ return __uint_as_float(u<<16); }
__device__ __forceinline__ float bu2f_hi(unsigned u){ return __uint_as_float(u & 0xffff0000u); }
__device__ __forceinline__ void w_hilo(u16* hi, u16* lo, int idx, float x) {
    u16 h = f2bu(x);
    hi[idx] = h;
    lo[idx] = f2bu(x - __uint_as_float(((unsigned)h) << 16));
}
// 16B fragment from an 8B-aligned address: two b64 reads
__device__ __forceinline__ s16x8 ld2x64(const u16* p) {
    s16x4 a = *(const s16x4*)p;
    s16x4 b = *(const s16x4*)(p + 4);
    s16x8 r;
    r[0]=a[0]; r[1]=a[1]; r[2]=a[2]; r[3]=a[3];
    r[4]=b[0]; r[5]=b[1]; r[6]=b[2]; r[7]=b[3];
    return r;
}
#define MFMA(a,b,c) __builtin_amdgcn_mfma_f32_16x16x32_bf16(a,b,c,0,0,0)

__global__ __launch_bounds__(NTHR, 3) void fusion_kernel(
    const float* __restrict__ slot, const float* __restrict__ fq,
    const float* __restrict__ ipw,  const float* __restrict__ ipb,
    const float* __restrict__ opw,  const float* __restrict__ opb,
    const float* __restrict__ lnqg, const float* __restrict__ lnqb,
    const float* __restrict__ lnkg, const float* __restrict__ lnkb,
    const float* __restrict__ wih,  const float* __restrict__ whh,
    const float* __restrict__ bih,  const float* __restrict__ bhh,
    const float* __restrict__ sigr, const float* __restrict__ praw,
    const float* __restrict__ p1w,  const float* __restrict__ p1b,
    const float* __restrict__ p2w,  const float* __restrict__ p2b,
    float* __restrict__ outp, const int M)
{
    // ---- block-wide weights ----
    __shared__ __align__(16) u16 s_wkv[96*WKV_ST];
    __shared__ __align__(16) u16 s_wq [48*WQ_ST];
    __shared__ __align__(16) u16 s_whn[48*WHN_ST];
    __shared__ __align__(16) u16 s_wcat[144*WC_ST];
    __shared__ __align__(16) u16 s_p1[48*P_ST];
    __shared__ __align__(16) u16 s_p2[48*P_ST];
    __shared__ __align__(16) u16 zblk[8];
    __shared__ float s_bg[144];
    __shared__ __align__(16) float s_lnqg[48], s_lnqb[48];
    __shared__ __align__(16) float s_lnkg[48], s_lnkb[48];
    __shared__ float s_sig[48], s_p1b[48], s_p2b[48], s_fq[48];
    __shared__ float s_pp;
    // ---- per-wave scratch ----
    __shared__ __align__(16) u16   s_kv [NWAVE][NS*KV_ST];  // kvn hi, then K overlay
    __shared__ __align__(16) u16   s_un [NWAVE][UN_SZ];     // kvn lo plane, then V^T
    __shared__ __align__(16) u16   s_qnh[NWAVE][64];
    __shared__ __align__(16) u16   s_qnl[NWAVE][64];
    __shared__ __align__(16) u16   s_xch[NWAVE][112];
    __shared__ __align__(16) u16   s_xcl[NWAVE][112];
    __shared__ __align__(16) float s_Qv [NWAVE][48];
    __shared__ __align__(16) float s_aw [NWAVE][64];
    __shared__ __align__(16) float s_g1 [NWAVE][144];
    __shared__ __align__(16) float s_g2 [NWAVE][48];

    const int tid = threadIdx.x;
    for (int i = tid; i < 48*WQ_ST; i += NTHR) {
        int r = i / WQ_ST, c = i - r*WQ_ST;
        s_wq[i] = f2bu(c < 48 ? ipw[r*48+c] : (c == 48 ? ipb[r] : 0.f));
    }
    for (int i = tid; i < 96*WKV_ST; i += NTHR) {
        int r = i / WKV_ST, c = i - r*WKV_ST;
        s_wkv[i] = f2bu(c < 48 ? ipw[(48+r)*48+c] : (c == 48 ? ipb[48+r] : 0.f));
    }
    for (int i = tid; i < 48*WHN_ST; i += NTHR) {
        int r = i / WHN_ST, c = i - r*WHN_ST;
        s_whn[i] = f2bu(c < 48 ? whh[(96+r)*48+c] : (c == 48 ? bhh[96+r] : 0.f));
    }
    for (int i = tid; i < 144*WC_ST; i += NTHR) {
        int r = i / WC_ST, c = i - r*WC_ST;
        float v = 0.f;
        if (c < 48) { float a = 0.f;
            for (int t = 0; t < 48; ++t) a = fmaf(wih[r*48+t], opw[t*48+c], a);
            v = a;
        } else if (c < 96 && r < 96) v = whh[r*48 + (c-48)];
        s_wcat[i] = f2bu(v);
    }
    for (int i = tid; i < 48*P_ST; i += NTHR) {
        int r = i / P_ST, c = i - r*P_ST;
        s_p1[i] = f2bu(c < 48 ? p1w[r*48+c] : 0.f);
        s_p2[i] = f2bu(c < 48 ? p2w[r*48+c] : 0.f);
    }
    if (tid < 144) {
        float a = bih[tid] + (tid < 96 ? bhh[tid] : 0.f);
        for (int t = 0; t < 48; ++t) a = fmaf(wih[tid*48+t], opb[t], a);
        s_bg[tid] = a;
    }
    if (tid < 48) {
        s_lnqg[tid] = lnqg[tid]; s_lnqb[tid] = lnqb[tid];
        s_lnkg[tid] = lnkg[tid]; s_lnkb[tid] = lnkb[tid];
        s_sig[tid] = log1pf(__expf(sigr[tid])) + 0.01f;
        s_p1b[tid] = p1b[tid]; s_p2b[tid] = p2b[tid];
        s_fq[tid] = fq[tid];
    }
    if (tid < 8) zblk[tid] = 0;
    if (tid == 0) s_pp = 1.5f + log1pf(__expf(praw[0]));
    __syncthreads();

    const int w = tid >> 6, l = tid & 63;
    const int jl = (l < DM) ? l : 0;
    const int g = l >> 4, u = l & 15, lm = l & 15, g8 = (l >> 4)*8;
    u16* __restrict__ kv = s_kv[w];
    u16* un = s_un[w];       // UNION: kvn-lo plane AND V^T; single pointer, NO restrict
    u16* __restrict__ qnh = s_qnh[w];
    u16* __restrict__ qnl = s_qnl[w];
    u16* __restrict__ xch = s_xch[w];
    u16* __restrict__ xcl = s_xcl[w];
    float* __restrict__ Qv = s_Qv[w];
    float* __restrict__ aw = s_aw[w];
    float* __restrict__ vg1 = s_g1[w];
    float* __restrict__ vg2 = s_g2[w];

    // one-time per-wave inits: whole union buffer finite (NaN guard), kv bias col
    for (int e = l; e < UN_SZ; e += 64) un[e] = 0;
    for (int e = l; e < NS*8; e += 64) {
        int s = e >> 3, c = e & 7;
        kv[s*KV_ST + 48 + c] = (c == 0) ? (u16)0x3F80 : (u16)0;
    }
    if (l >= 48) { qnh[l] = (l == 48) ? (u16)0x3F80 : (u16)0; qnl[l] = 0; }
    if (l < 16)  { xch[96 + l] = (l == 0) ? (u16)0x3F80 : (u16)0; xcl[96 + l] = 0; }

    const float pexp = s_pp, pinv = 1.0f / s_pp;
    const int h2 = (jl >= HDm) ? 1 : 0;
    const int sh = l >> 5, snn = l & 31;
    const bool sact = snn < NS;
    const int sn = sact ? snn : 0;

    for (int m = blockIdx.x*NWAVE + w; m < M; m += gridDim.x*NWAVE) {
        const float* __restrict__ kvp = slot + (size_t)m * (NS*DM);

        // ---- LN(kv) -> kv hi + un lo planes (cols 0-47), hoisted ----
        #pragma unroll
        for (int i = 0; i < 6; ++i) {
            int n = i*4 + g;
            bool act = (n < NS);
            int nc = act ? n : 0;
            float x0 = kvp[nc*DM + u], x1 = kvp[nc*DM + 16 + u], x2 = kvp[nc*DM + 32 + u];
            float s1 = x0 + x1 + x2;
            float s2 = x0*x0 + x1*x1 + x2*x2;
            #pragma unroll
            for (int off = 8; off; off >>= 1) {
                s1 += __shfl_xor(s1, off);
                s2 += __shfl_xor(s2, off);
            }
            float mu = s1 * (1.f/48.f);
            float rs = rsqrtf(s2 * (1.f/48.f) - mu*mu + 1e-5f);
            if (act) {
                w_hilo(kv, un, nc*KV_ST + u,      (x0 - mu)*rs*s_lnkg[u]    + s_lnkb[u]);
                w_hilo(kv, un, nc*KV_ST + 16 + u, (x1 - mu)*rs*s_lnkg[16+u] + s_lnkb[16+u]);
                w_hilo(kv, un, nc*KV_ST + 32 + u, (x2 - mu)*rs*s_lnkg[32+u] + s_lnkb[32+u]);
            }
        }

        // ---- K,V via MFMA: A=wkv bf16, B=kvn hi+lo (effective fp32) ----
        s16x8 Bh[2][2], Bl[2][2];
        #pragma unroll
        for (int nt = 0; nt < 2; ++nt) {
            int sl = lm + nt*16; if (sl > NS-1) sl = NS-1;   // clamped: D discarded
            Bh[nt][0] = ld2x64(&kv[sl*KV_ST + g8]);
            Bh[nt][1] = (g8 < 24) ? ld2x64(&kv[sl*KV_ST + 32 + g8])
                                  : *(const s16x8*)zblk;
            Bl[nt][0] = ld2x64(&un[sl*KV_ST + g8]);
            Bl[nt][1] = (g8 < 16) ? ld2x64(&un[sl*KV_ST + 32 + g8])
                                  : *(const s16x8*)zblk;   // lo of bias cols = 0
        }
        #pragma unroll
        for (int mt = 0; mt < 6; ++mt) {
            const u16* ar = &s_wkv[(mt*16 + lm)*WKV_ST];
            s16x8 A0 = *(const s16x8*)&ar[g8];
            s16x8 A1 = (g8 < 24) ? *(const s16x8*)&ar[32 + g8] : *(const s16x8*)zblk;
            #pragma unroll
            for (int nt = 0; nt < 2; ++nt) {
                f32x4 acc = {0.f, 0.f, 0.f, 0.f};
                acc = MFMA(A0, Bh[nt][0], acc);
                acc = MFMA(A1, Bh[nt][1], acc);
                acc = MFMA(A0, Bl[nt][0], acc);
                acc = MFMA(A1, Bl[nt][1], acc);
                int slotn = lm + nt*16;
                if (slotn < NS) {
                    if (mt < 3) {        // K -> overlay kv cols 0-47 (B reads done)
                        uint2 pk;
                        pk.x = (unsigned)f2bu(acc[0]) | ((unsigned)f2bu(acc[1]) << 16);
                        pk.y = (unsigned)f2bu(acc[2]) | ((unsigned)f2bu(acc[3]) << 16);
                        *(uint2*)&kv[slotn*KV_ST + mt*16 + g*4] = pk;
                    } else {             // V -> transposed store into union buffer
                        int ch = (mt-3)*16 + g*4;
                        un[(ch+0)*VT_ST + slotn] = f2bu(acc[0]);
                        un[(ch+1)*VT_ST + slotn] = f2bu(acc[1]);
                        un[(ch+2)*VT_ST + slotn] = f2bu(acc[2]);
                        un[(ch+3)*VT_ST + slotn] = f2bu(acc[3]);
                    }
                }
            }
        }

        // ---- 3 GRU-attention iterations ----
        float qreg = s_fq[jl];
        if (l < DM) w_hilo(xch, xcl, 48 + l, qreg);
        #pragma unroll 1
        for (int it = 0; it < ITERS; ++it) {
            // LN(q)
            float xq = (l < DM) ? qreg : 0.f;
            float s1 = xq, s2 = xq*xq;
            #pragma unroll
            for (int off = 32; off; off >>= 1) {
                s1 += __shfl_xor(s1, off);
                s2 += __shfl_xor(s2, off);
            }
            float mu = s1 * (1.f/48.f);
            float rs = rsqrtf(s2 * (1.f/48.f) - mu*mu + 1e-5f);
            if (l < DM) w_hilo(qnh, qnl, l, (xq - mu)*rs*s_lnqg[jl] + s_lnqb[jl]);
            // Q = MFMA(wq, qn hi+lo); bias via qn[48]=1, wq col48=bq
            s16x8 Bq0h = *(const s16x8*)&qnh[g8];
            s16x8 Bq1h = *(const s16x8*)&qnh[32 + g8];
            s16x8 Bq0l = *(const s16x8*)&qnl[g8];
            s16x8 Bq1l = *(const s16x8*)&qnl[32 + g8];
            #pragma unroll
            for (int mt = 0; mt < 3; ++mt) {
                const u16* ar = &s_wq[(mt*16 + lm)*WQ_ST];
                s16x8 A0 = *(const s16x8*)&ar[g8];
                s16x8 A1 = (g8 < 24) ? *(const s16x8*)&ar[32 + g8] : *(const s16x8*)zblk;
                f32x4 acc = {0.f, 0.f, 0.f, 0.f};
                acc = MFMA(A0, Bq0h, acc);
                acc = MFMA(A1, Bq1h, acc);
                acc = MFMA(A0, Bq0l, acc);
                acc = MFMA(A1, Bq1l, acc);
                if (lm == 0) *(f32x4*)&Qv[mt*16 + g*4] = acc;
            }
            // scores + softmax (lane = head*32 + slot); stride-60 K rows: ~2-way banks
            float dt = 0.f;
            #pragma unroll
            for (int d4 = 0; d4 < 6; ++d4) {
                float4 q4 = *(const float4*)&Qv[sh*HDm + d4*4];
                uint2 ku = *(const uint2*)&kv[sn*KV_ST + sh*HDm + d4*4];
                dt = fmaf(q4.x, bu2f_lo(ku.x), dt);
                dt = fmaf(q4.y, bu2f_hi(ku.x), dt);
                dt = fmaf(q4.z, bu2f_lo(ku.y), dt);
                dt = fmaf(q4.w, bu2f_hi(ku.y), dt);
            }
            float sc = sact ? dt * 0.20412414523193154f : -3.0e38f;
            float mx = sc;
            #pragma unroll
            for (int off = 16; off; off >>= 1) mx = fmaxf(mx, __shfl_xor(mx, off));
            float ex = __expf(sc - mx);
            float se = ex;
            #pragma unroll
            for (int off = 16; off; off >>= 1) se += __shfl_xor(se, off);
            aw[l] = ex / se;    // lanes snn>=21 get exactly 0
            // attn via V^T: b64 reads at stride 28 u16; pad cols * aw=0
            float at = 0.f;
            #pragma unroll
            for (int b = 0; b < 6; ++b) {
                uint2 vv = *(const uint2*)&un[jl*VT_ST + b*4];
                const float* ap = &aw[h2*32 + b*4];
                float2 a0 = *(const float2*)(ap + 0);
                float2 a1 = *(const float2*)(ap + 2);
                at = fmaf(a0.x, bu2f_lo(vv.x), at);
                at = fmaf(a0.y, bu2f_hi(vv.x), at);
                at = fmaf(a1.x, bu2f_lo(vv.y), at);
                at = fmaf(a1.y, bu2f_hi(vv.y), at);
            }
            if (l < DM) w_hilo(xch, xcl, l, at);
            // GRU: vg1[0:96]=r,z pre-act; vg1[96:144]=i_n; h_n separate (vg2)
            s16x8 Bc0h = *(const s16x8*)&xch[g8];
            s16x8 Bc1h = *(const s16x8*)&xch[32 + g8];
            s16x8 Bc2h = *(const s16x8*)&xch[64 + g8];
            s16x8 Bc0l = *(const s16x8*)&xcl[g8];
            s16x8 Bc1l = *(const s16x8*)&xcl[32 + g8];
            s16x8 Bc2l = *(const s16x8*)&xcl[64 + g8];
            #pragma unroll 3
            for (int mt = 0; mt < 9; ++mt) {
                const u16* ar = &s_wcat[(mt*16 + lm)*WC_ST];
                s16x8 A0 = *(const s16x8*)&ar[g8];
                s16x8 A1 = *(const s16x8*)&ar[32 + g8];
                f32x4 acc = {0.f, 0.f, 0.f, 0.f};
                acc = MFMA(A0, Bc0h, acc);
                acc = MFMA(A1, Bc1h, acc);
                acc = MFMA(A0, Bc0l, acc);
                acc = MFMA(A1, Bc1l, acc);
                if (mt < 6) {
                    s16x8 A2 = *(const s16x8*)&ar[64 + g8];
                    acc = MFMA(A2, Bc2h, acc);
                    acc = MFMA(A2, Bc2l, acc);
                }
                if (lm == 0) *(f32x4*)&vg1[mt*16 + g*4] = acc;
            }
            s16x8 Bh0h = *(const s16x8*)&xch[48 + g8];
            s16x8 Bh1h = *(const s16x8*)&xch[80 + g8];  // g2: xch[96]=1 bias, g3: zeros
            s16x8 Bh0l = *(const s16x8*)&xcl[48 + g8];
            s16x8 Bh1l = *(const s16x8*)&xcl[80 + g8];
            #pragma unroll
            for (int mt = 0; mt < 3; ++mt) {
                const u16* ar = &s_whn[(mt*16 + lm)*WHN_ST];
                s16x8 A0 = *(const s16x8*)&ar[g8];
                s16x8 A1 = (g8 < 24) ? *(const s16x8*)&ar[32 + g8] : *(const s16x8*)zblk;
                f32x4 acc = {0.f, 0.f, 0.f, 0.f};
                acc = MFMA(A0, Bh0h, acc);
                acc = MFMA(A1, Bh1h, acc);
                acc = MFMA(A0, Bh0l, acc);
                acc = MFMA(A1, Bh1l, acc);
                if (lm == 0) *(f32x4*)&vg2[mt*16 + g*4] = acc;
            }
            float yr = vg1[jl]      + s_bg[jl];
            float yz = vg1[48 + jl] + s_bg[48 + jl];
            float yn = vg1[96 + jl] + s_bg[96 + jl];
            float hn = vg2[jl];
            float r = 1.f / (1.f + __expf(-yr));
            float z = 1.f / (1.f + __expf(-yz));
            float nn = tanhf(yn + r*hn);
            qreg = (1.f - z)*nn + z*qreg;
            if (l < DM) w_hilo(xch, xcl, 48 + l, qreg);
        }

        // ---- outputs ----
        if (l < NS)
            outp[(size_t)M*DM + (size_t)m*NS + l] = 0.5f*(aw[l] + aw[32 + l]);
        float f = qreg;
        float ratio = fminf(fabsf(f) / s_sig[jl], 15.f);
        float rp = __powf(ratio, pexp);
        f = f / __powf(1.f + rp, pinv);
        if (l < DM) Qv[l] = f;      // Qv reused as tail vx (Q dead)
        float4 a4 = {0,0,0,0};
        #pragma unroll
        for (int d4 = 0; d4 < 12; ++d4) {
            uint2 rw = *(const uint2*)&s_p1[jl*P_ST + d4*4];
            float4 x4 = *(const float4*)&Qv[d4*4];
            a4.x = fmaf(bu2f_lo(rw.x), x4.x, a4.x);
            a4.y = fmaf(bu2f_hi(rw.x), x4.y, a4.y);
            a4.z = fmaf(bu2f_lo(rw.y), x4.z, a4.z);
            a4.w = fmaf(bu2f_hi(rw.y), x4.w, a4.w);
        }
        float h1 = fmaxf(0.f, s_p1b[jl] + (a4.x + a4.y) + (a4.z + a4.w));
        if (l < DM) Qv[l] = h1;
        float4 c4 = {0,0,0,0};
        #pragma unroll
        for (int d4 = 0; d4 < 12; ++d4) {
            uint2 rw = *(const uint2*)&s_p2[jl*P_ST + d4*4];
            float4 x4 = *(const float4*)&Qv[d4*4];
            c4.x = fmaf(bu2f_lo(rw.x), x4.x, c4.x);
            c4.y = fmaf(bu2f_hi(rw.x), x4.y, c4.y);
            c4.z = fmaf(bu2f_lo(rw.y), x4.z, c4.z);
            c4.w = fmaf(bu2f_hi(rw.y), x4.w, c4.w);
        }
        if (l < DM) outp[(size_t)m*DM + l] = s_p2b[jl] + (c4.x + c4.y) + (c4.z + c4.w);
    }
}

extern "C" void kernel_launch(void* const* d_in, const int* in_sizes, int n_in,
                              void* d_out, int out_size, void* d_ws, size_t ws_size,
                              hipStream_t stream) {
    const float* slot = (const float*)d_in[0];
    const float* fq   = (const float*)d_in[1];
    const float* ipw  = (const float*)d_in[2];
    const float* ipb  = (const float*)d_in[3];
    const float* opw  = (const float*)d_in[4];
    const float* opb  = (const float*)d_in[5];
    const float* lnqg = (const float*)d_in[6];
    const float* lnqb = (const float*)d_in[7];
    const float* lnkg = (const float*)d_in[8];
    const float* lnkb = (const float*)d_in[9];
    const float* wih  = (const float*)d_in[10];
    const float* whh  = (const float*)d_in[11];
    const float* bihp = (const float*)d_in[12];
    const float* bhhp = (const float*)d_in[13];
    const float* sigr = (const float*)d_in[14];
    const float* praw = (const float*)d_in[15];
    const float* p1w  = (const float*)d_in[16];
    const float* p1b  = (const float*)d_in[17];
    const float* p2w  = (const float*)d_in[18];
    const float* p2b  = (const float*)d_in[19];
    const int M = in_sizes[0] / (NS*DM);   // 65536
    fusion_kernel<<<dim3(256), dim3(NTHR), 0, stream>>>(
        slot, fq, ipw, ipb, opw, opb, lnqg, lnqb, lnkg, lnkb,
        wih, whh, bihp, bhhp, sigr, praw, p1w, p1b, p2w, p2b,
        (float*)d_out, M);
}

// Round 16
// 503.084 us; speedup vs baseline: 1.2614x; 1.2614x over previous
//
#include <hip/hip_runtime.h>
#include <hip/hip_bf16.h>

#define DM 48
#define NS 21
#define HDm 24
#define ITERS 3
#define NWAVE 12   // 768 thr = 12 waves = 3/SIMD: proven no-spill point (84 VGPR cap)
#define NTHR (NWAVE*64)

#define KV_ST 56   // kvn/K row stride (u16); col48 = 1.0 (bias one), 49-55 = 0
#define VT_ST 28   // V^T row stride (u16): best measured (r14: 561us bench)
#define UN_SZ 1344 // max(NS*KV_ST=1176, 48*VT_ST=1344)
#define WKV_ST 56
#define WQ_ST 56
#define WHN_ST 56
#define WC_ST 104
#define P_ST 52

typedef short s16x8 __attribute__((ext_vector_type(8)));
typedef float f32x4 __attribute__((ext_vector_type(4)));
typedef unsigned short u16;

__device__ __forceinline__ u16 f2bu(float f) {
    __hip_bfloat16 h = __float2bfloat16(f);
    return *reinterpret_cast<u16*>(&h);
}
__device__ __forceinline__ float bu2f_lo(unsigned u){ return __uint_as_float(u<<16); }
__device__ __forceinline__ float bu2f_hi(unsigned u){ return __uint_as_float(u & 0xffff0000u); }
__device__ __forceinline__ void w_hilo(u16* hi, u16* lo, int idx, float x) {
    u16 h = f2bu(x);
    hi[idx] = h;
    lo[idx] = f2bu(x - __uint_as_float(((unsigned)h) << 16));
}
#define MFMA(a,b,c) __builtin_amdgcn_mfma_f32_16x16x32_bf16(a,b,c,0,0,0)

__global__ __launch_bounds__(NTHR, 3) void fusion_kernel(
    const float* __restrict__ slot, const float* __restrict__ fq,
    const float* __restrict__ ipw,  const float* __restrict__ ipb,
    const float* __restrict__ opw,  const float* __restrict__ opb,
    const float* __restrict__ lnqg, const float* __restrict__ lnqb,
    const float* __restrict__ lnkg, const float* __restrict__ lnkb,
    const float* __restrict__ wih,  const float* __restrict__ whh,
    const float* __restrict__ bih,  const float* __restrict__ bhh,
    const float* __restrict__ sigr, const float* __restrict__ praw,
    const float* __restrict__ p1w,  const float* __restrict__ p1b,
    const float* __restrict__ p2w,  const float* __restrict__ p2b,
    float* __restrict__ outp, const int M)
{
    // ---- block-wide weights (r6/r14 layout) ----
    __shared__ __align__(16) u16 s_wkv[96*WKV_ST];
    __shared__ __align__(16) u16 s_wq [48*WQ_ST];
    __shared__ __align__(16) u16 s_whn[48*WHN_ST];
    __shared__ __align__(16) u16 s_wcat[144*WC_ST];
    __shared__ __align__(16) u16 s_p1[48*P_ST];
    __shared__ __align__(16) u16 s_p2[48*P_ST];
    __shared__ __align__(16) u16 zblk[8];
    __shared__ float s_bg[144];
    __shared__ __align__(16) float s_lnqg[48], s_lnqb[48];
    __shared__ __align__(16) float s_lnkg[48], s_lnkb[48];
    __shared__ float s_sig[48], s_p1b[48], s_p2b[48], s_fq[48];
    __shared__ float s_pp;
    // ---- per-wave scratch ----
    __shared__ __align__(16) u16   s_kv [NWAVE][NS*KV_ST];  // kvn hi, then K overlay
    __shared__ __align__(16) u16   s_un [NWAVE][UN_SZ];     // kvn lo plane, then V^T
    __shared__ __align__(16) u16   s_qnh[NWAVE][64];
    __shared__ __align__(16) u16   s_qnl[NWAVE][64];
    __shared__ __align__(16) u16   s_xch[NWAVE][112];
    __shared__ __align__(16) u16   s_xcl[NWAVE][112];
    __shared__ __align__(16) float s_Qv [NWAVE][48];
    __shared__ __align__(16) float s_aw [NWAVE][64];
    __shared__ __align__(16) float s_g1 [NWAVE][144];
    __shared__ __align__(16) float s_g2 [NWAVE][48];

    const int tid = threadIdx.x;
    for (int i = tid; i < 48*WQ_ST; i += NTHR) {
        int r = i / WQ_ST, c = i - r*WQ_ST;
        s_wq[i] = f2bu(c < 48 ? ipw[r*48+c] : (c == 48 ? ipb[r] : 0.f));
    }
    for (int i = tid; i < 96*WKV_ST; i += NTHR) {
        int r = i / WKV_ST, c = i - r*WKV_ST;
        s_wkv[i] = f2bu(c < 48 ? ipw[(48+r)*48+c] : (c == 48 ? ipb[48+r] : 0.f));
    }
    for (int i = tid; i < 48*WHN_ST; i += NTHR) {
        int r = i / WHN_ST, c = i - r*WHN_ST;
        s_whn[i] = f2bu(c < 48 ? whh[(96+r)*48+c] : (c == 48 ? bhh[96+r] : 0.f));
    }
    for (int i = tid; i < 144*WC_ST; i += NTHR) {
        int r = i / WC_ST, c = i - r*WC_ST;
        float v = 0.f;
        if (c < 48) { float a = 0.f;
            for (int t = 0; t < 48; ++t) a = fmaf(wih[r*48+t], opw[t*48+c], a);
            v = a;
        } else if (c < 96 && r < 96) v = whh[r*48 + (c-48)];
        s_wcat[i] = f2bu(v);
    }
    for (int i = tid; i < 48*P_ST; i += NTHR) {
        int r = i / P_ST, c = i - r*P_ST;
        s_p1[i] = f2bu(c < 48 ? p1w[r*48+c] : 0.f);
        s_p2[i] = f2bu(c < 48 ? p2w[r*48+c] : 0.f);
    }
    if (tid < 144) {
        float a = bih[tid] + (tid < 96 ? bhh[tid] : 0.f);
        for (int t = 0; t < 48; ++t) a = fmaf(wih[tid*48+t], opb[t], a);
        s_bg[tid] = a;
    }
    if (tid < 48) {
        s_lnqg[tid] = lnqg[tid]; s_lnqb[tid] = lnqb[tid];
        s_lnkg[tid] = lnkg[tid]; s_lnkb[tid] = lnkb[tid];
        s_sig[tid] = log1pf(__expf(sigr[tid])) + 0.01f;
        s_p1b[tid] = p1b[tid]; s_p2b[tid] = p2b[tid];
        s_fq[tid] = fq[tid];
    }
    if (tid < 8) zblk[tid] = 0;
    if (tid == 0) s_pp = 1.5f + log1pf(__expf(praw[0]));
    __syncthreads();

    const int w = tid >> 6, l = tid & 63;
    const int jl = (l < DM) ? l : 0;
    const int g = l >> 4, u = l & 15, lm = l & 15, g8 = (l >> 4)*8;
    u16* __restrict__ kv = s_kv[w];
    u16* un = s_un[w];       // UNION: kvn-lo plane AND V^T; single pointer, NO restrict
    u16* __restrict__ qnh = s_qnh[w];
    u16* __restrict__ qnl = s_qnl[w];
    u16* __restrict__ xch = s_xch[w];
    u16* __restrict__ xcl = s_xcl[w];
    float* __restrict__ Qv = s_Qv[w];
    float* __restrict__ aw = s_aw[w];
    float* __restrict__ vg1 = s_g1[w];
    float* __restrict__ vg2 = s_g2[w];

    // one-time per-wave inits: whole union buffer finite (NaN guard), kv bias col
    for (int e = l; e < UN_SZ; e += 64) un[e] = 0;
    for (int e = l; e < NS*8; e += 64) {
        int s = e >> 3, c = e & 7;
        kv[s*KV_ST + 48 + c] = (c == 0) ? (u16)0x3F80 : (u16)0;
    }
    if (l >= 48) { qnh[l] = (l == 48) ? (u16)0x3F80 : (u16)0; qnl[l] = 0; }
    if (l < 16)  { xch[96 + l] = (l == 0) ? (u16)0x3F80 : (u16)0; xcl[96 + l] = 0; }

    const float pexp = s_pp, pinv = 1.0f / s_pp;
    const int h2 = (jl >= HDm) ? 1 : 0;
    const int sh = l >> 5, snn = l & 31;
    const bool sact = snn < NS;
    const int sn = sact ? snn : 0;

    for (int m = blockIdx.x*NWAVE + w; m < M; m += gridDim.x*NWAVE) {
        const float* __restrict__ kvp = slot + (size_t)m * (NS*DM);

        // ---- LN(kv) -> kv hi + un lo planes (cols 0-47), hoisted ----
        #pragma unroll
        for (int i = 0; i < 6; ++i) {
            int n = i*4 + g;
            bool act = (n < NS);
            int nc = act ? n : 0;
            float x0 = kvp[nc*DM + u], x1 = kvp[nc*DM + 16 + u], x2 = kvp[nc*DM + 32 + u];
            float s1 = x0 + x1 + x2;
            float s2 = x0*x0 + x1*x1 + x2*x2;
            #pragma unroll
            for (int off = 8; off; off >>= 1) {
                s1 += __shfl_xor(s1, off);
                s2 += __shfl_xor(s2, off);
            }
            float mu = s1 * (1.f/48.f);
            float rs = rsqrtf(s2 * (1.f/48.f) - mu*mu + 1e-5f);
            if (act) {
                w_hilo(kv, un, nc*KV_ST + u,      (x0 - mu)*rs*s_lnkg[u]    + s_lnkb[u]);
                w_hilo(kv, un, nc*KV_ST + 16 + u, (x1 - mu)*rs*s_lnkg[16+u] + s_lnkb[16+u]);
                w_hilo(kv, un, nc*KV_ST + 32 + u, (x2 - mu)*rs*s_lnkg[32+u] + s_lnkb[32+u]);
            }
        }

        // ---- K,V via MFMA: A=wkv bf16, B=kvn hi+lo (effective fp32) ----
        s16x8 Bh[2][2], Bl[2][2];
        #pragma unroll
        for (int nt = 0; nt < 2; ++nt) {
            int sl = lm + nt*16; if (sl > NS-1) sl = NS-1;   // clamped: D discarded
            Bh[nt][0] = *(const s16x8*)&kv[sl*KV_ST + g8];
            Bh[nt][1] = (g8 < 24) ? *(const s16x8*)&kv[sl*KV_ST + 32 + g8]
                                  : *(const s16x8*)zblk;
            Bl[nt][0] = *(const s16x8*)&un[sl*KV_ST + g8];
            Bl[nt][1] = (g8 < 16) ? *(const s16x8*)&un[sl*KV_ST + 32 + g8]
                                  : *(const s16x8*)zblk;   // lo of bias cols = 0
        }
        __builtin_amdgcn_s_setprio(1);   // MFMA-heavy phase: prefer this wave (T5)
        #pragma unroll
        for (int mt = 0; mt < 6; ++mt) {
            const u16* ar = &s_wkv[(mt*16 + lm)*WKV_ST];
            s16x8 A0 = *(const s16x8*)&ar[g8];
            s16x8 A1 = (g8 < 24) ? *(const s16x8*)&ar[32 + g8] : *(const s16x8*)zblk;
            #pragma unroll
            for (int nt = 0; nt < 2; ++nt) {
                f32x4 acc = {0.f, 0.f, 0.f, 0.f};
                acc = MFMA(A0, Bh[nt][0], acc);
                acc = MFMA(A1, Bh[nt][1], acc);
                acc = MFMA(A0, Bl[nt][0], acc);
                acc = MFMA(A1, Bl[nt][1], acc);
                int slotn = lm + nt*16;
                if (slotn < NS) {
                    if (mt < 3) {        // K -> overlay kv cols 0-47 (B reads done)
                        uint2 pk;
                        pk.x = (unsigned)f2bu(acc[0]) | ((unsigned)f2bu(acc[1]) << 16);
                        pk.y = (unsigned)f2bu(acc[2]) | ((unsigned)f2bu(acc[3]) << 16);
                        *(uint2*)&kv[slotn*KV_ST + mt*16 + g*4] = pk;
                    } else {             // V -> transposed store into union buffer
                        int ch = (mt-3)*16 + g*4;
                        un[(ch+0)*VT_ST + slotn] = f2bu(acc[0]);
                        un[(ch+1)*VT_ST + slotn] = f2bu(acc[1]);
                        un[(ch+2)*VT_ST + slotn] = f2bu(acc[2]);
                        un[(ch+3)*VT_ST + slotn] = f2bu(acc[3]);
                    }
                }
            }
        }
        __builtin_amdgcn_s_setprio(0);

        // ---- 3 GRU-attention iterations ----
        float qreg = s_fq[jl];
        if (l < DM) w_hilo(xch, xcl, 48 + l, qreg);
        #pragma unroll 1
        for (int it = 0; it < ITERS; ++it) {
            // LN(q)
            float xq = (l < DM) ? qreg : 0.f;
            float s1 = xq, s2 = xq*xq;
            #pragma unroll
            for (int off = 32; off; off >>= 1) {
                s1 += __shfl_xor(s1, off);
                s2 += __shfl_xor(s2, off);
            }
            float mu = s1 * (1.f/48.f);
            float rs = rsqrtf(s2 * (1.f/48.f) - mu*mu + 1e-5f);
            if (l < DM) w_hilo(qnh, qnl, l, (xq - mu)*rs*s_lnqg[jl] + s_lnqb[jl]);
            // Q = MFMA(wq, qn hi+lo); bias via qn[48]=1, wq col48=bq
            s16x8 Bq0h = *(const s16x8*)&qnh[g8];
            s16x8 Bq1h = *(const s16x8*)&qnh[32 + g8];
            s16x8 Bq0l = *(const s16x8*)&qnl[g8];
            s16x8 Bq1l = *(const s16x8*)&qnl[32 + g8];
            __builtin_amdgcn_s_setprio(1);
            #pragma unroll
            for (int mt = 0; mt < 3; ++mt) {
                const u16* ar = &s_wq[(mt*16 + lm)*WQ_ST];
                s16x8 A0 = *(const s16x8*)&ar[g8];
                s16x8 A1 = (g8 < 24) ? *(const s16x8*)&ar[32 + g8] : *(const s16x8*)zblk;
                f32x4 acc = {0.f, 0.f, 0.f, 0.f};
                acc = MFMA(A0, Bq0h, acc);
                acc = MFMA(A1, Bq1h, acc);
                acc = MFMA(A0, Bq0l, acc);
                acc = MFMA(A1, Bq1l, acc);
                if (lm == 0) *(f32x4*)&Qv[mt*16 + g*4] = acc;
            }
            __builtin_amdgcn_s_setprio(0);
            // scores + softmax (lane = head*32 + slot)
            float dt = 0.f;
            #pragma unroll
            for (int d4 = 0; d4 < 6; ++d4) {
                float4 q4 = *(const float4*)&Qv[sh*HDm + d4*4];
                uint2 ku = *(const uint2*)&kv[sn*KV_ST + sh*HDm + d4*4];
                dt = fmaf(q4.x, bu2f_lo(ku.x), dt);
                dt = fmaf(q4.y, bu2f_hi(ku.x), dt);
                dt = fmaf(q4.z, bu2f_lo(ku.y), dt);
                dt = fmaf(q4.w, bu2f_hi(ku.y), dt);
            }
            float sc = sact ? dt * 0.20412414523193154f : -3.0e38f;
            float mx = sc;
            #pragma unroll
            for (int off = 16; off; off >>= 1) mx = fmaxf(mx, __shfl_xor(mx, off));
            float ex = __expf(sc - mx);
            float se = ex;
            #pragma unroll
            for (int off = 16; off; off >>= 1) se += __shfl_xor(se, off);
            aw[l] = ex / se;    // lanes snn>=21 get exactly 0
            // attn via V^T: b64 reads at stride 28 u16; pad cols * aw=0
            float at = 0.f;
            #pragma unroll
            for (int b = 0; b < 6; ++b) {
                uint2 vv = *(const uint2*)&un[jl*VT_ST + b*4];
                const float* ap = &aw[h2*32 + b*4];
                float2 a0 = *(const float2*)(ap + 0);
                float2 a1 = *(const float2*)(ap + 2);
                at = fmaf(a0.x, bu2f_lo(vv.x), at);
                at = fmaf(a0.y, bu2f_hi(vv.x), at);
                at = fmaf(a1.x, bu2f_lo(vv.y), at);
                at = fmaf(a1.y, bu2f_hi(vv.y), at);
            }
            if (l < DM) w_hilo(xch, xcl, l, at);
            // GRU: vg1[0:96]=r,z pre-act; vg1[96:144]=i_n; h_n separate (vg2)
            s16x8 Bc0h = *(const s16x8*)&xch[g8];
            s16x8 Bc1h = *(const s16x8*)&xch[32 + g8];
            s16x8 Bc2h = *(const s16x8*)&xch[64 + g8];
            s16x8 Bc0l = *(const s16x8*)&xcl[g8];
            s16x8 Bc1l = *(const s16x8*)&xcl[32 + g8];
            s16x8 Bc2l = *(const s16x8*)&xcl[64 + g8];
            __builtin_amdgcn_s_setprio(1);
            #pragma unroll 3
            for (int mt = 0; mt < 9; ++mt) {
                const u16* ar = &s_wcat[(mt*16 + lm)*WC_ST];
                s16x8 A0 = *(const s16x8*)&ar[g8];
                s16x8 A1 = *(const s16x8*)&ar[32 + g8];
                f32x4 acc = {0.f, 0.f, 0.f, 0.f};
                acc = MFMA(A0, Bc0h, acc);
                acc = MFMA(A1, Bc1h, acc);
                acc = MFMA(A0, Bc0l, acc);
                acc = MFMA(A1, Bc1l, acc);
                if (mt < 6) {
                    s16x8 A2 = *(const s16x8*)&ar[64 + g8];
                    acc = MFMA(A2, Bc2h, acc);
                    acc = MFMA(A2, Bc2l, acc);
                }
                if (lm == 0) *(f32x4*)&vg1[mt*16 + g*4] = acc;
            }
            s16x8 Bh0h = *(const s16x8*)&xch[48 + g8];
            s16x8 Bh1h = *(const s16x8*)&xch[80 + g8];  // g2: xch[96]=1 bias, g3: zeros
            s16x8 Bh0l = *(const s16x8*)&xcl[48 + g8];
            s16x8 Bh1l = *(const s16x8*)&xcl[80 + g8];
            #pragma unroll
            for (int mt = 0; mt < 3; ++mt) {
                const u16* ar = &s_whn[(mt*16 + lm)*WHN_ST];
                s16x8 A0 = *(const s16x8*)&ar[g8];
                s16x8 A1 = (g8 < 24) ? *(const s16x8*)&ar[32 + g8] : *(const s16x8*)zblk;
                f32x4 acc = {0.f, 0.f, 0.f, 0.f};
                acc = MFMA(A0, Bh0h, acc);
                acc = MFMA(A1, Bh1h, acc);
                acc = MFMA(A0, Bh0l, acc);
                acc = MFMA(A1, Bh1l, acc);
                if (lm == 0) *(f32x4*)&vg2[mt*16 + g*4] = acc;
            }
            __builtin_amdgcn_s_setprio(0);
            float yr = vg1[jl]      + s_bg[jl];
            float yz = vg1[48 + jl] + s_bg[48 + jl];
            float yn = vg1[96 + jl] + s_bg[96 + jl];
            float hn = vg2[jl];
            float r = 1.f / (1.f + __expf(-yr));
            float z = 1.f / (1.f + __expf(-yz));
            float nn = tanhf(yn + r*hn);
            qreg = (1.f - z)*nn + z*qreg;
            if (l < DM) w_hilo(xch, xcl, 48 + l, qreg);
        }

        // ---- outputs ----
        if (l < NS)
            outp[(size_t)M*DM + (size_t)m*NS + l] = 0.5f*(aw[l] + aw[32 + l]);
        float f = qreg;
        float ratio = fminf(fabsf(f) / s_sig[jl], 15.f);
        float rp = __powf(ratio, pexp);
        f = f / __powf(1.f + rp, pinv);
        if (l < DM) Qv[l] = f;      // Qv reused as tail vx (Q dead)
        float4 a4 = {0,0,0,0};
        #pragma unroll
        for (int d4 = 0; d4 < 12; ++d4) {
            uint2 rw = *(const uint2*)&s_p1[jl*P_ST + d4*4];
            float4 x4 = *(const float4*)&Qv[d4*4];
            a4.x = fmaf(bu2f_lo(rw.x), x4.x, a4.x);
            a4.y = fmaf(bu2f_hi(rw.x), x4.y, a4.y);
            a4.z = fmaf(bu2f_lo(rw.y), x4.z, a4.z);
            a4.w = fmaf(bu2f_hi(rw.y), x4.w, a4.w);
        }
        float h1 = fmaxf(0.f, s_p1b[jl] + (a4.x + a4.y) + (a4.z + a4.w));
        if (l < DM) Qv[l] = h1;
        float4 c4 = {0,0,0,0};
        #pragma unroll
        for (int d4 = 0; d4 < 12; ++d4) {
            uint2 rw = *(const uint2*)&s_p2[jl*P_ST + d4*4];
            float4 x4 = *(const float4*)&Qv[d4*4];
            c4.x = fmaf(bu2f_lo(rw.x), x4.x, c4.x);
            c4.y = fmaf(bu2f_hi(rw.x), x4.y, c4.y);
            c4.z = fmaf(bu2f_lo(rw.y), x4.z, c4.z);
            c4.w = fmaf(bu2f_hi(rw.y), x4.w, c4.w);
        }
        if (l < DM) outp[(size_t)m*DM + l] = s_p2b[jl] + (c4.x + c4.y) + (c4.z + c4.w);
    }
}

extern "C" void kernel_launch(void* const* d_in, const int* in_sizes, int n_in,
                              void* d_out, int out_size, void* d_ws, size_t ws_size,
                              hipStream_t stream) {
    const float* slot = (const float*)d_in[0];
    const float* fq   = (const float*)d_in[1];
    const float* ipw  = (const float*)d_in[2];
    const float* ipb  = (const float*)d_in[3];
    const float* opw  = (const float*)d_in[4];
    const float* opb  = (const float*)d_in[5];
    const float* lnqg = (const float*)d_in[6];
    const float* lnqb = (const float*)d_in[7];
    const float* lnkg = (const float*)d_in[8];
    const float* lnkb = (const float*)d_in[9];
    const float* wih  = (const float*)d_in[10];
    const float* whh  = (const float*)d_in[11];
    const float* bihp = (const float*)d_in[12];
    const float* bhhp = (const float*)d_in[13];
    const float* sigr = (const float*)d_in[14];
    const float* praw = (const float*)d_in[15];
    const float* p1w  = (const float*)d_in[16];
    const float* p1b  = (const float*)d_in[17];
    const float* p2w  = (const float*)d_in[18];
    const float* p2b  = (const float*)d_in[19];
    const int M = in_sizes[0] / (NS*DM);   // 65536
    fusion_kernel<<<dim3(256), dim3(NTHR), 0, stream>>>(
        slot, fq, ipw, ipb, opw, opb, lnqg, lnqb, lnkg, lnkb,
        wih, whh, bihp, bhhp, sigr, praw, p1w, p1b, p2w, p2b,
        (float*)d_out, M);
}

// Round 17
// 490.374 us; speedup vs baseline: 1.2941x; 1.0259x over previous
//
#include <hip/hip_runtime.h>
#include <hip/hip_bf16.h>

#define DM 48
#define NS 21
#define HDm 24
#define ITERS 3
#define NWAVE 12   // 768 thr = 12 waves = 3/SIMD: proven no-spill point (84 VGPR cap)
#define NTHR (NWAVE*64)

#define KV_ST 56   // kvn/K row stride (u16); col48 = 1.0 (bias one), 49-55 = 0
#define VT_ST 28   // V^T row stride (u16)
#define UN_SZ 1344 // max(NS*KV_ST=1176, 48*VT_ST=1344)
#define WKV_ST 56
#define WQ_ST 56
#define WHN_ST 56
#define WC_ST 104
#define P_ST 52

typedef short s16x8 __attribute__((ext_vector_type(8)));
typedef float f32x4 __attribute__((ext_vector_type(4)));
typedef unsigned short u16;

__device__ __forceinline__ u16 f2bu(float f) {
    __hip_bfloat16 h = __float2bfloat16(f);
    return *reinterpret_cast<u16*>(&h);
}
__device__ __forceinline__ float bu2f_lo(unsigned u){ return __uint_as_float(u<<16); }
__device__ __forceinline__ float bu2f_hi(unsigned u){ return __uint_as_float(u & 0xffff0000u); }
__device__ __forceinline__ void w_hilo(u16* hi, u16* lo, int idx, float x) {
    u16 h = f2bu(x);
    hi[idx] = h;
    lo[idx] = f2bu(x - __uint_as_float(((unsigned)h) << 16));
}
// overflow-free fast tanh: e^{-2|x|} <= 1 always
__device__ __forceinline__ float ftanh(float x) {
    float t = __expf(-2.0f * fabsf(x));
    float r = (1.0f - t) / (1.0f + t);
    return copysignf(r, x);
}
#define MFMA(a,b,c) __builtin_amdgcn_mfma_f32_16x16x32_bf16(a,b,c,0,0,0)

__global__ __launch_bounds__(NTHR, 3) void fusion_kernel(
    const float* __restrict__ slot, const float* __restrict__ fq,
    const float* __restrict__ ipw,  const float* __restrict__ ipb,
    const float* __restrict__ opw,  const float* __restrict__ opb,
    const float* __restrict__ lnqg, const float* __restrict__ lnqb,
    const float* __restrict__ lnkg, const float* __restrict__ lnkb,
    const float* __restrict__ wih,  const float* __restrict__ whh,
    const float* __restrict__ bih,  const float* __restrict__ bhh,
    const float* __restrict__ sigr, const float* __restrict__ praw,
    const float* __restrict__ p1w,  const float* __restrict__ p1b,
    const float* __restrict__ p2w,  const float* __restrict__ p2b,
    float* __restrict__ outp, const int M)
{
    // ---- block-wide weights (r16 layout) ----
    __shared__ __align__(16) u16 s_wkv[96*WKV_ST];
    __shared__ __align__(16) u16 s_wq [48*WQ_ST];
    __shared__ __align__(16) u16 s_whn[48*WHN_ST];
    __shared__ __align__(16) u16 s_wcat[144*WC_ST];
    __shared__ __align__(16) u16 s_p1[48*P_ST];
    __shared__ __align__(16) u16 s_p2[48*P_ST];
    __shared__ __align__(16) u16 zblk[8];
    __shared__ float s_bg[144];
    __shared__ __align__(16) float s_lnqg[48], s_lnqb[48];
    __shared__ __align__(16) float s_lnkg[48], s_lnkb[48];
    __shared__ float s_sig[48], s_p1b[48], s_p2b[48], s_fq[48];
    __shared__ float s_pp;
    // ---- per-wave scratch ----
    __shared__ __align__(16) u16   s_kv [NWAVE][NS*KV_ST];  // kvn hi, then K overlay
    __shared__ __align__(16) u16   s_un [NWAVE][UN_SZ];     // kvn lo plane, then V^T
    __shared__ __align__(16) u16   s_qnh[NWAVE][64];
    __shared__ __align__(16) u16   s_qnl[NWAVE][64];
    __shared__ __align__(16) u16   s_xch[NWAVE][112];
    __shared__ __align__(16) u16   s_xcl[NWAVE][112];
    __shared__ __align__(16) float s_Qv [NWAVE][48];
    __shared__ __align__(16) float s_aw [NWAVE][64];
    __shared__ __align__(16) float s_g1 [NWAVE][144];
    __shared__ __align__(16) float s_g2 [NWAVE][48];

    const int tid = threadIdx.x;
    for (int i = tid; i < 48*WQ_ST; i += NTHR) {
        int r = i / WQ_ST, c = i - r*WQ_ST;
        s_wq[i] = f2bu(c < 48 ? ipw[r*48+c] : (c == 48 ? ipb[r] : 0.f));
    }
    for (int i = tid; i < 96*WKV_ST; i += NTHR) {
        int r = i / WKV_ST, c = i - r*WKV_ST;
        s_wkv[i] = f2bu(c < 48 ? ipw[(48+r)*48+c] : (c == 48 ? ipb[48+r] : 0.f));
    }
    for (int i = tid; i < 48*WHN_ST; i += NTHR) {
        int r = i / WHN_ST, c = i - r*WHN_ST;
        s_whn[i] = f2bu(c < 48 ? whh[(96+r)*48+c] : (c == 48 ? bhh[96+r] : 0.f));
    }
    for (int i = tid; i < 144*WC_ST; i += NTHR) {
        int r = i / WC_ST, c = i - r*WC_ST;
        float v = 0.f;
        if (c < 48) { float a = 0.f;
            for (int t = 0; t < 48; ++t) a = fmaf(wih[r*48+t], opw[t*48+c], a);
            v = a;
        } else if (c < 96 && r < 96) v = whh[r*48 + (c-48)];
        s_wcat[i] = f2bu(v);
    }
    for (int i = tid; i < 48*P_ST; i += NTHR) {
        int r = i / P_ST, c = i - r*P_ST;
        s_p1[i] = f2bu(c < 48 ? p1w[r*48+c] : 0.f);
        s_p2[i] = f2bu(c < 48 ? p2w[r*48+c] : 0.f);
    }
    if (tid < 144) {
        float a = bih[tid] + (tid < 96 ? bhh[tid] : 0.f);
        for (int t = 0; t < 48; ++t) a = fmaf(wih[tid*48+t], opb[t], a);
        s_bg[tid] = a;
    }
    if (tid < 48) {
        s_lnqg[tid] = lnqg[tid]; s_lnqb[tid] = lnqb[tid];
        s_lnkg[tid] = lnkg[tid]; s_lnkb[tid] = lnkb[tid];
        s_sig[tid] = log1pf(__expf(sigr[tid])) + 0.01f;
        s_p1b[tid] = p1b[tid]; s_p2b[tid] = p2b[tid];
        s_fq[tid] = fq[tid];
    }
    if (tid < 8) zblk[tid] = 0;
    if (tid == 0) s_pp = 1.5f + log1pf(__expf(praw[0]));
    __syncthreads();

    const int w = tid >> 6, l = tid & 63;
    const int jl = (l < DM) ? l : 0;
    const int g = l >> 4, u = l & 15, lm = l & 15, g8 = (l >> 4)*8;
    u16* __restrict__ kv = s_kv[w];
    u16* un = s_un[w];       // UNION: kvn-lo plane AND V^T; single pointer, NO restrict
    u16* __restrict__ qnh = s_qnh[w];
    u16* __restrict__ qnl = s_qnl[w];
    u16* __restrict__ xch = s_xch[w];
    u16* __restrict__ xcl = s_xcl[w];
    float* __restrict__ Qv = s_Qv[w];
    float* __restrict__ aw = s_aw[w];
    float* __restrict__ vg1 = s_g1[w];
    float* __restrict__ vg2 = s_g2[w];

    // one-time per-wave inits: whole union buffer finite (NaN guard), kv bias col
    for (int e = l; e < UN_SZ; e += 64) un[e] = 0;
    for (int e = l; e < NS*8; e += 64) {
        int s = e >> 3, c = e & 7;
        kv[s*KV_ST + 48 + c] = (c == 0) ? (u16)0x3F80 : (u16)0;
    }
    if (l >= 48) { qnh[l] = (l == 48) ? (u16)0x3F80 : (u16)0; qnl[l] = 0; }
    if (l < 16)  { xch[96 + l] = (l == 0) ? (u16)0x3F80 : (u16)0; xcl[96 + l] = 0; }

    const float pexp = s_pp, pinv = 1.0f / s_pp;
    const int h2 = (jl >= HDm) ? 1 : 0;
    const int sh = l >> 5, snn = l & 31;
    const bool sact = snn < NS;
    const int sn = sact ? snn : 0;

    for (int m = blockIdx.x*NWAVE + w; m < M; m += gridDim.x*NWAVE) {
        const float* __restrict__ kvp = slot + (size_t)m * (NS*DM);

        // ---- LN(kv) -> kv hi + un lo planes (cols 0-47), hoisted ----
        #pragma unroll
        for (int i = 0; i < 6; ++i) {
            int n = i*4 + g;
            bool act = (n < NS);
            int nc = act ? n : 0;
            float x0 = kvp[nc*DM + u], x1 = kvp[nc*DM + 16 + u], x2 = kvp[nc*DM + 32 + u];
            float s1 = x0 + x1 + x2;
            float s2 = x0*x0 + x1*x1 + x2*x2;
            #pragma unroll
            for (int off = 8; off; off >>= 1) {
                s1 += __shfl_xor(s1, off);
                s2 += __shfl_xor(s2, off);
            }
            float mu = s1 * (1.f/48.f);
            float rs = rsqrtf(s2 * (1.f/48.f) - mu*mu + 1e-5f);
            if (act) {
                w_hilo(kv, un, nc*KV_ST + u,      (x0 - mu)*rs*s_lnkg[u]    + s_lnkb[u]);
                w_hilo(kv, un, nc*KV_ST + 16 + u, (x1 - mu)*rs*s_lnkg[16+u] + s_lnkb[16+u]);
                w_hilo(kv, un, nc*KV_ST + 32 + u, (x2 - mu)*rs*s_lnkg[32+u] + s_lnkb[32+u]);
            }
        }

        // ---- K,V via MFMA: A=wkv bf16, B=kvn hi+lo (effective fp32) ----
        s16x8 Bh[2][2], Bl[2][2];
        #pragma unroll
        for (int nt = 0; nt < 2; ++nt) {
            int sl = lm + nt*16; if (sl > NS-1) sl = NS-1;   // clamped: D discarded
            Bh[nt][0] = *(const s16x8*)&kv[sl*KV_ST + g8];
            Bh[nt][1] = (g8 < 24) ? *(const s16x8*)&kv[sl*KV_ST + 32 + g8]
                                  : *(const s16x8*)zblk;
            Bl[nt][0] = *(const s16x8*)&un[sl*KV_ST + g8];
            Bl[nt][1] = (g8 < 16) ? *(const s16x8*)&un[sl*KV_ST + 32 + g8]
                                  : *(const s16x8*)zblk;   // lo of bias cols = 0
        }
        __builtin_amdgcn_s_setprio(1);   // MFMA-heavy phase (T5, r16-proven)
        #pragma unroll
        for (int mt = 0; mt < 6; ++mt) {
            const u16* ar = &s_wkv[(mt*16 + lm)*WKV_ST];
            s16x8 A0 = *(const s16x8*)&ar[g8];
            s16x8 A1 = (g8 < 24) ? *(const s16x8*)&ar[32 + g8] : *(const s16x8*)zblk;
            #pragma unroll
            for (int nt = 0; nt < 2; ++nt) {
                f32x4 acc = {0.f, 0.f, 0.f, 0.f};
                acc = MFMA(A0, Bh[nt][0], acc);
                acc = MFMA(A1, Bh[nt][1], acc);
                acc = MFMA(A0, Bl[nt][0], acc);
                acc = MFMA(A1, Bl[nt][1], acc);
                int slotn = lm + nt*16;
                if (slotn < NS) {
                    if (mt < 3) {        // K -> overlay kv cols 0-47 (B reads done)
                        uint2 pk;
                        pk.x = (unsigned)f2bu(acc[0]) | ((unsigned)f2bu(acc[1]) << 16);
                        pk.y = (unsigned)f2bu(acc[2]) | ((unsigned)f2bu(acc[3]) << 16);
                        *(uint2*)&kv[slotn*KV_ST + mt*16 + g*4] = pk;
                    } else {             // V -> transposed store into union buffer
                        int ch = (mt-3)*16 + g*4;
                        un[(ch+0)*VT_ST + slotn] = f2bu(acc[0]);
                        un[(ch+1)*VT_ST + slotn] = f2bu(acc[1]);
                        un[(ch+2)*VT_ST + slotn] = f2bu(acc[2]);
                        un[(ch+3)*VT_ST + slotn] = f2bu(acc[3]);
                    }
                }
            }
        }
        __builtin_amdgcn_s_setprio(0);

        // ---- 3 GRU-attention iterations ----
        float qreg = s_fq[jl];
        if (l < DM) w_hilo(xch, xcl, 48 + l, qreg);
        #pragma unroll 1
        for (int it = 0; it < ITERS; ++it) {
            // LN(q)
            float xq = (l < DM) ? qreg : 0.f;
            float s1 = xq, s2 = xq*xq;
            #pragma unroll
            for (int off = 32; off; off >>= 1) {
                s1 += __shfl_xor(s1, off);
                s2 += __shfl_xor(s2, off);
            }
            float mu = s1 * (1.f/48.f);
            float rs = rsqrtf(s2 * (1.f/48.f) - mu*mu + 1e-5f);
            if (l < DM) w_hilo(qnh, qnl, l, (xq - mu)*rs*s_lnqg[jl] + s_lnqb[jl]);
            // Q = MFMA(wq, qn hi+lo); bias via qn[48]=1, wq col48=bq
            s16x8 Bq0h = *(const s16x8*)&qnh[g8];
            s16x8 Bq1h = *(const s16x8*)&qnh[32 + g8];
            s16x8 Bq0l = *(const s16x8*)&qnl[g8];
            s16x8 Bq1l = *(const s16x8*)&qnl[32 + g8];
            __builtin_amdgcn_s_setprio(1);
            #pragma unroll
            for (int mt = 0; mt < 3; ++mt) {
                const u16* ar = &s_wq[(mt*16 + lm)*WQ_ST];
                s16x8 A0 = *(const s16x8*)&ar[g8];
                s16x8 A1 = (g8 < 24) ? *(const s16x8*)&ar[32 + g8] : *(const s16x8*)zblk;
                f32x4 acc = {0.f, 0.f, 0.f, 0.f};
                acc = MFMA(A0, Bq0h, acc);
                acc = MFMA(A1, Bq1h, acc);
                acc = MFMA(A0, Bq0l, acc);
                acc = MFMA(A1, Bq1l, acc);
                if (lm == 0) *(f32x4*)&Qv[mt*16 + g*4] = acc;
            }
            __builtin_amdgcn_s_setprio(0);
            // scores + softmax, NO max-subtraction: |sc| <~ 6 on LN'd data, exp-safe
            float dt = 0.f;
            #pragma unroll
            for (int d4 = 0; d4 < 6; ++d4) {
                float4 q4 = *(const float4*)&Qv[sh*HDm + d4*4];
                uint2 ku = *(const uint2*)&kv[sn*KV_ST + sh*HDm + d4*4];
                dt = fmaf(q4.x, bu2f_lo(ku.x), dt);
                dt = fmaf(q4.y, bu2f_hi(ku.x), dt);
                dt = fmaf(q4.z, bu2f_lo(ku.y), dt);
                dt = fmaf(q4.w, bu2f_hi(ku.y), dt);
            }
            float ex = sact ? __expf(dt * 0.20412414523193154f) : 0.f;
            float se = ex;
            #pragma unroll
            for (int off = 16; off; off >>= 1) se += __shfl_xor(se, off);
            aw[l] = ex / se;    // lanes snn>=21 get exactly 0
            // attn via V^T: b64 reads at stride 28 u16; pad cols * aw=0
            float at = 0.f;
            #pragma unroll
            for (int b = 0; b < 6; ++b) {
                uint2 vv = *(const uint2*)&un[jl*VT_ST + b*4];
                const float* ap = &aw[h2*32 + b*4];
                float2 a0 = *(const float2*)(ap + 0);
                float2 a1 = *(const float2*)(ap + 2);
                at = fmaf(a0.x, bu2f_lo(vv.x), at);
                at = fmaf(a0.y, bu2f_hi(vv.x), at);
                at = fmaf(a1.x, bu2f_lo(vv.y), at);
                at = fmaf(a1.y, bu2f_hi(vv.y), at);
            }
            if (l < DM) w_hilo(xch, xcl, l, at);
            // GRU: vg1[0:96]=r,z pre-act; vg1[96:144]=i_n; h_n separate (vg2)
            s16x8 Bc0h = *(const s16x8*)&xch[g8];
            s16x8 Bc1h = *(const s16x8*)&xch[32 + g8];
            s16x8 Bc2h = *(const s16x8*)&xch[64 + g8];
            s16x8 Bc0l = *(const s16x8*)&xcl[g8];
            s16x8 Bc1l = *(const s16x8*)&xcl[32 + g8];
            s16x8 Bc2l = *(const s16x8*)&xcl[64 + g8];
            __builtin_amdgcn_s_setprio(1);
            #pragma unroll 3
            for (int mt = 0; mt < 9; ++mt) {
                const u16* ar = &s_wcat[(mt*16 + lm)*WC_ST];
                s16x8 A0 = *(const s16x8*)&ar[g8];
                s16x8 A1 = *(const s16x8*)&ar[32 + g8];
                f32x4 acc = {0.f, 0.f, 0.f, 0.f};
                acc = MFMA(A0, Bc0h, acc);
                acc = MFMA(A1, Bc1h, acc);
                acc = MFMA(A0, Bc0l, acc);
                acc = MFMA(A1, Bc1l, acc);
                if (mt < 6) {
                    s16x8 A2 = *(const s16x8*)&ar[64 + g8];
                    acc = MFMA(A2, Bc2h, acc);
                    acc = MFMA(A2, Bc2l, acc);
                }
                if (lm == 0) *(f32x4*)&vg1[mt*16 + g*4] = acc;
            }
            s16x8 Bh0h = *(const s16x8*)&xch[48 + g8];
            s16x8 Bh1h = *(const s16x8*)&xch[80 + g8];  // g2: xch[96]=1 bias, g3: zeros
            s16x8 Bh0l = *(const s16x8*)&xcl[48 + g8];
            s16x8 Bh1l = *(const s16x8*)&xcl[80 + g8];
            #pragma unroll
            for (int mt = 0; mt < 3; ++mt) {
                const u16* ar = &s_whn[(mt*16 + lm)*WHN_ST];
                s16x8 A0 = *(const s16x8*)&ar[g8];
                s16x8 A1 = (g8 < 24) ? *(const s16x8*)&ar[32 + g8] : *(const s16x8*)zblk;
                f32x4 acc = {0.f, 0.f, 0.f, 0.f};
                acc = MFMA(A0, Bh0h, acc);
                acc = MFMA(A1, Bh1h, acc);
                acc = MFMA(A0, Bh0l, acc);
                acc = MFMA(A1, Bh1l, acc);
                if (lm == 0) *(f32x4*)&vg2[mt*16 + g*4] = acc;
            }
            __builtin_amdgcn_s_setprio(0);
            float yr = vg1[jl]      + s_bg[jl];
            float yz = vg1[48 + jl] + s_bg[48 + jl];
            float yn = vg1[96 + jl] + s_bg[96 + jl];
            float hn = vg2[jl];
            float r = 1.f / (1.f + __expf(-yr));
            float z = 1.f / (1.f + __expf(-yz));
            float nn = ftanh(yn + r*hn);
            qreg = (1.f - z)*nn + z*qreg;
            if (l < DM) w_hilo(xch, xcl, 48 + l, qreg);
        }

        // ---- outputs ----
        if (l < NS)
            outp[(size_t)M*DM + (size_t)m*NS + l] = 0.5f*(aw[l] + aw[32 + l]);
        float f = qreg;
        float ratio = fminf(fabsf(f) / s_sig[jl], 15.f);
        float rp = __powf(ratio, pexp);
        f = f / __powf(1.f + rp, pinv);
        if (l < DM) Qv[l] = f;      // Qv reused as tail vx (Q dead)
        float4 a4 = {0,0,0,0};
        #pragma unroll
        for (int d4 = 0; d4 < 12; ++d4) {
            uint2 rw = *(const uint2*)&s_p1[jl*P_ST + d4*4];
            float4 x4 = *(const float4*)&Qv[d4*4];
            a4.x = fmaf(bu2f_lo(rw.x), x4.x, a4.x);
            a4.y = fmaf(bu2f_hi(rw.x), x4.y, a4.y);
            a4.z = fmaf(bu2f_lo(rw.y), x4.z, a4.z);
            a4.w = fmaf(bu2f_hi(rw.y), x4.w, a4.w);
        }
        float h1 = fmaxf(0.f, s_p1b[jl] + (a4.x + a4.y) + (a4.z + a4.w));
        if (l < DM) Qv[l] = h1;
        float4 c4 = {0,0,0,0};
        #pragma unroll
        for (int d4 = 0; d4 < 12; ++d4) {
            uint2 rw = *(const uint2*)&s_p2[jl*P_ST + d4*4];
            float4 x4 = *(const float4*)&Qv[d4*4];
            c4.x = fmaf(bu2f_lo(rw.x), x4.x, c4.x);
            c4.y = fmaf(bu2f_hi(rw.x), x4.y, c4.y);
            c4.z = fmaf(bu2f_lo(rw.y), x4.z, c4.z);
            c4.w = fmaf(bu2f_hi(rw.y), x4.w, c4.w);
        }
        if (l < DM) outp[(size_t)m*DM + l] = s_p2b[jl] + (c4.x + c4.y) + (c4.z + c4.w);
    }
}

extern "C" void kernel_launch(void* const* d_in, const int* in_sizes, int n_in,
                              void* d_out, int out_size, void* d_ws, size_t ws_size,
                              hipStream_t stream) {
    const float* slot = (const float*)d_in[0];
    const float* fq   = (const float*)d_in[1];
    const float* ipw  = (const float*)d_in[2];
    const float* ipb  = (const float*)d_in[3];
    const float* opw  = (const float*)d_in[4];
    const float* opb  = (const float*)d_in[5];
    const float* lnqg = (const float*)d_in[6];
    const float* lnqb = (const float*)d_in[7];
    const float* lnkg = (const float*)d_in[8];
    const float* lnkb = (const float*)d_in[9];
    const float* wih  = (const float*)d_in[10];
    const float* whh  = (const float*)d_in[11];
    const float* bihp = (const float*)d_in[12];
    const float* bhhp = (const float*)d_in[13];
    const float* sigr = (const float*)d_in[14];
    const float* praw = (const float*)d_in[15];
    const float* p1w  = (const float*)d_in[16];
    const float* p1b  = (const float*)d_in[17];
    const float* p2w  = (const float*)d_in[18];
    const float* p2b  = (const float*)d_in[19];
    const int M = in_sizes[0] / (NS*DM);   // 65536
    fusion_kernel<<<dim3(256), dim3(NTHR), 0, stream>>>(
        slot, fq, ipw, ipb, opw, opb, lnqg, lnqb, lnkg, lnkb,
        wih, whh, bihp, bhhp, sigr, praw, p1w, p1b, p2w, p2b,
        (float*)d_out, M);
}

// Round 18
// 450.790 us; speedup vs baseline: 1.4077x; 1.0878x over previous
//
#include <hip/hip_runtime.h>
#include <hip/hip_bf16.h>

#define DM 48
#define NS 21
#define HDm 24
#define ITERS 3
#define NWAVE 12   // 768 thr = 12 waves = 3/SIMD: proven no-spill point (84 VGPR cap)
#define NTHR (NWAVE*64)

#define KV_ST 56   // kvn/K row stride (u16); col48 = 1.0 (bias one), 49-55 = 0
#define VT_ST 28   // V^T row stride (u16)
#define UN_SZ 1344 // max(NS*KV_ST=1176, 48*VT_ST=1344)
#define WKV_ST 56
#define WQ_ST 56
#define WHN_ST 56
#define WC_ST 104
#define P_ST 52

typedef short s16x8 __attribute__((ext_vector_type(8)));
typedef float f32x4 __attribute__((ext_vector_type(4)));
typedef unsigned short u16;

__device__ __forceinline__ u16 f2bu(float f) {
    __hip_bfloat16 h = __float2bfloat16(f);
    return *reinterpret_cast<u16*>(&h);
}
__device__ __forceinline__ float bu2f_lo(unsigned u){ return __uint_as_float(u<<16); }
__device__ __forceinline__ float bu2f_hi(unsigned u){ return __uint_as_float(u & 0xffff0000u); }
__device__ __forceinline__ void w_hilo(u16* hi, u16* lo, int idx, float x) {
    u16 h = f2bu(x);
    hi[idx] = h;
    lo[idx] = f2bu(x - __uint_as_float(((unsigned)h) << 16));
}
// overflow-free fast tanh: e^{-2|x|} <= 1 always
__device__ __forceinline__ float ftanh(float x) {
    float t = __expf(-2.0f * fabsf(x));
    float r = (1.0f - t) / (1.0f + t);
    return copysignf(r, x);
}
// DPP 16-lane reduce, r7-PROVEN sequence: xor1(0xB1) pairs; xor2(0x4E) 4-groups;
// half_mirror(0x141) crosses 4-boundary within each 8; row_mirror(0x140) crosses
// the 8-boundary. (r10's bug -- second within-8 op instead of 0x140 -- avoided.)
template<int C>
__device__ __forceinline__ float dppf(float x) {
    return __builtin_bit_cast(float,
        __builtin_amdgcn_update_dpp(0, __builtin_bit_cast(int, x), C, 0xF, 0xF, true));
}
__device__ __forceinline__ float row16_sum(float x) {
    x += dppf<0xB1>(x); x += dppf<0x4E>(x); x += dppf<0x141>(x); x += dppf<0x140>(x);
    return x;
}
#define MFMA(a,b,c) __builtin_amdgcn_mfma_f32_16x16x32_bf16(a,b,c,0,0,0)

__global__ __launch_bounds__(NTHR, 3) void fusion_kernel(
    const float* __restrict__ slot, const float* __restrict__ fq,
    const float* __restrict__ ipw,  const float* __restrict__ ipb,
    const float* __restrict__ opw,  const float* __restrict__ opb,
    const float* __restrict__ lnqg, const float* __restrict__ lnqb,
    const float* __restrict__ lnkg, const float* __restrict__ lnkb,
    const float* __restrict__ wih,  const float* __restrict__ whh,
    const float* __restrict__ bih,  const float* __restrict__ bhh,
    const float* __restrict__ sigr, const float* __restrict__ praw,
    const float* __restrict__ p1w,  const float* __restrict__ p1b,
    const float* __restrict__ p2w,  const float* __restrict__ p2b,
    float* __restrict__ outp, const int M)
{
    // ---- block-wide weights (r17 layout) ----
    __shared__ __align__(16) u16 s_wkv[96*WKV_ST];
    __shared__ __align__(16) u16 s_wq [48*WQ_ST];
    __shared__ __align__(16) u16 s_whn[48*WHN_ST];
    __shared__ __align__(16) u16 s_wcat[144*WC_ST];
    __shared__ __align__(16) u16 s_p1[48*P_ST];
    __shared__ __align__(16) u16 s_p2[48*P_ST];
    __shared__ __align__(16) u16 zblk[8];
    __shared__ float s_bg[144];
    __shared__ __align__(16) float s_lnqg[48], s_lnqb[48];
    __shared__ __align__(16) float s_lnkg[48], s_lnkb[48];
    __shared__ float s_sig[48], s_p1b[48], s_p2b[48], s_fq[48];
    __shared__ float s_pp;
    // ---- per-wave scratch ----
    __shared__ __align__(16) u16   s_kv [NWAVE][NS*KV_ST];  // kvn hi, then K overlay
    __shared__ __align__(16) u16   s_un [NWAVE][UN_SZ];     // kvn lo plane, then V^T
    __shared__ __align__(16) u16   s_qnh[NWAVE][64];
    __shared__ __align__(16) u16   s_qnl[NWAVE][64];
    __shared__ __align__(16) u16   s_xch[NWAVE][112];
    __shared__ __align__(16) u16   s_xcl[NWAVE][112];
    __shared__ __align__(16) float s_Qv [NWAVE][48];
    __shared__ __align__(16) float s_aw [NWAVE][64];
    __shared__ __align__(16) float s_g1 [NWAVE][144];
    __shared__ __align__(16) float s_g2 [NWAVE][48];

    const int tid = threadIdx.x;
    for (int i = tid; i < 48*WQ_ST; i += NTHR) {
        int r = i / WQ_ST, c = i - r*WQ_ST;
        s_wq[i] = f2bu(c < 48 ? ipw[r*48+c] : (c == 48 ? ipb[r] : 0.f));
    }
    for (int i = tid; i < 96*WKV_ST; i += NTHR) {
        int r = i / WKV_ST, c = i - r*WKV_ST;
        s_wkv[i] = f2bu(c < 48 ? ipw[(48+r)*48+c] : (c == 48 ? ipb[48+r] : 0.f));
    }
    for (int i = tid; i < 48*WHN_ST; i += NTHR) {
        int r = i / WHN_ST, c = i - r*WHN_ST;
        s_whn[i] = f2bu(c < 48 ? whh[(96+r)*48+c] : (c == 48 ? bhh[96+r] : 0.f));
    }
    for (int i = tid; i < 144*WC_ST; i += NTHR) {
        int r = i / WC_ST, c = i - r*WC_ST;
        float v = 0.f;
        if (c < 48) { float a = 0.f;
            for (int t = 0; t < 48; ++t) a = fmaf(wih[r*48+t], opw[t*48+c], a);
            v = a;
        } else if (c < 96 && r < 96) v = whh[r*48 + (c-48)];
        s_wcat[i] = f2bu(v);
    }
    for (int i = tid; i < 48*P_ST; i += NTHR) {
        int r = i / P_ST, c = i - r*P_ST;
        s_p1[i] = f2bu(c < 48 ? p1w[r*48+c] : 0.f);
        s_p2[i] = f2bu(c < 48 ? p2w[r*48+c] : 0.f);
    }
    if (tid < 144) {
        float a = bih[tid] + (tid < 96 ? bhh[tid] : 0.f);
        for (int t = 0; t < 48; ++t) a = fmaf(wih[tid*48+t], opb[t], a);
        s_bg[tid] = a;
    }
    if (tid < 48) {
        s_lnqg[tid] = lnqg[tid]; s_lnqb[tid] = lnqb[tid];
        s_lnkg[tid] = lnkg[tid]; s_lnkb[tid] = lnkb[tid];
        s_sig[tid] = log1pf(__expf(sigr[tid])) + 0.01f;
        s_p1b[tid] = p1b[tid]; s_p2b[tid] = p2b[tid];
        s_fq[tid] = fq[tid];
    }
    if (tid < 8) zblk[tid] = 0;
    if (tid == 0) s_pp = 1.5f + log1pf(__expf(praw[0]));
    __syncthreads();

    const int w = tid >> 6, l = tid & 63;
    const int jl = (l < DM) ? l : 0;
    const int g = l >> 4, u = l & 15, lm = l & 15, g8 = (l >> 4)*8;
    u16* __restrict__ kv = s_kv[w];
    u16* un = s_un[w];       // UNION: kvn-lo plane AND V^T; single pointer, NO restrict
    u16* __restrict__ qnh = s_qnh[w];
    u16* __restrict__ qnl = s_qnl[w];
    u16* __restrict__ xch = s_xch[w];
    u16* __restrict__ xcl = s_xcl[w];
    float* __restrict__ Qv = s_Qv[w];
    float* __restrict__ aw = s_aw[w];
    float* __restrict__ vg1 = s_g1[w];
    float* __restrict__ vg2 = s_g2[w];

    // one-time per-wave inits: whole union buffer finite (NaN guard), kv bias col
    for (int e = l; e < UN_SZ; e += 64) un[e] = 0;
    for (int e = l; e < NS*8; e += 64) {
        int s = e >> 3, c = e & 7;
        kv[s*KV_ST + 48 + c] = (c == 0) ? (u16)0x3F80 : (u16)0;
    }
    if (l >= 48) { qnh[l] = (l == 48) ? (u16)0x3F80 : (u16)0; qnl[l] = 0; }
    if (l < 16)  { xch[96 + l] = (l == 0) ? (u16)0x3F80 : (u16)0; xcl[96 + l] = 0; }

    const float pexp = s_pp, pinv = 1.0f / s_pp;
    const int h2 = (jl >= HDm) ? 1 : 0;
    const int sh = l >> 5, snn = l & 31;
    const bool sact = snn < NS;
    const int sn = sact ? snn : 0;

    for (int m = blockIdx.x*NWAVE + w; m < M; m += gridDim.x*NWAVE) {
        const float* __restrict__ kvp = slot + (size_t)m * (NS*DM);

        // ---- LN(kv) -> kv hi + un lo planes (cols 0-47), hoisted; DPP reduce ----
        #pragma unroll
        for (int i = 0; i < 6; ++i) {
            int n = i*4 + g;
            bool act = (n < NS);
            int nc = act ? n : 0;
            float x0 = kvp[nc*DM + u], x1 = kvp[nc*DM + 16 + u], x2 = kvp[nc*DM + 32 + u];
            float s1 = row16_sum(x0 + x1 + x2);
            float s2 = row16_sum(x0*x0 + x1*x1 + x2*x2);
            float mu = s1 * (1.f/48.f);
            float rs = rsqrtf(s2 * (1.f/48.f) - mu*mu + 1e-5f);
            if (act) {
                w_hilo(kv, un, nc*KV_ST + u,      (x0 - mu)*rs*s_lnkg[u]    + s_lnkb[u]);
                w_hilo(kv, un, nc*KV_ST + 16 + u, (x1 - mu)*rs*s_lnkg[16+u] + s_lnkb[16+u]);
                w_hilo(kv, un, nc*KV_ST + 32 + u, (x2 - mu)*rs*s_lnkg[32+u] + s_lnkb[32+u]);
            }
        }

        // ---- K,V via MFMA: A=wkv bf16, B=kvn hi+lo (effective fp32) ----
        s16x8 Bh[2][2], Bl[2][2];
        #pragma unroll
        for (int nt = 0; nt < 2; ++nt) {
            int sl = lm + nt*16; if (sl > NS-1) sl = NS-1;   // clamped: D discarded
            Bh[nt][0] = *(const s16x8*)&kv[sl*KV_ST + g8];
            Bh[nt][1] = (g8 < 24) ? *(const s16x8*)&kv[sl*KV_ST + 32 + g8]
                                  : *(const s16x8*)zblk;
            Bl[nt][0] = *(const s16x8*)&un[sl*KV_ST + g8];
            Bl[nt][1] = (g8 < 16) ? *(const s16x8*)&un[sl*KV_ST + 32 + g8]
                                  : *(const s16x8*)zblk;   // lo of bias cols = 0
        }
        __builtin_amdgcn_s_setprio(1);   // MFMA-heavy phase (T5, r16-proven)
        #pragma unroll
        for (int mt = 0; mt < 6; ++mt) {
            const u16* ar = &s_wkv[(mt*16 + lm)*WKV_ST];
            s16x8 A0 = *(const s16x8*)&ar[g8];
            s16x8 A1 = (g8 < 24) ? *(const s16x8*)&ar[32 + g8] : *(const s16x8*)zblk;
            #pragma unroll
            for (int nt = 0; nt < 2; ++nt) {
                f32x4 acc = {0.f, 0.f, 0.f, 0.f};
                acc = MFMA(A0, Bh[nt][0], acc);
                acc = MFMA(A1, Bh[nt][1], acc);
                acc = MFMA(A0, Bl[nt][0], acc);
                acc = MFMA(A1, Bl[nt][1], acc);
                int slotn = lm + nt*16;
                if (slotn < NS) {
                    if (mt < 3) {        // K -> overlay kv cols 0-47 (B reads done)
                        uint2 pk;
                        pk.x = (unsigned)f2bu(acc[0]) | ((unsigned)f2bu(acc[1]) << 16);
                        pk.y = (unsigned)f2bu(acc[2]) | ((unsigned)f2bu(acc[3]) << 16);
                        *(uint2*)&kv[slotn*KV_ST + mt*16 + g*4] = pk;
                    } else {             // V -> transposed store into union buffer
                        int ch = (mt-3)*16 + g*4;
                        un[(ch+0)*VT_ST + slotn] = f2bu(acc[0]);
                        un[(ch+1)*VT_ST + slotn] = f2bu(acc[1]);
                        un[(ch+2)*VT_ST + slotn] = f2bu(acc[2]);
                        un[(ch+3)*VT_ST + slotn] = f2bu(acc[3]);
                    }
                }
            }
        }
        __builtin_amdgcn_s_setprio(0);

        // ---- 3 GRU-attention iterations ----
        float qreg = s_fq[jl];
        if (l < DM) w_hilo(xch, xcl, 48 + l, qreg);
        #pragma unroll 1
        for (int it = 0; it < ITERS; ++it) {
            // LN(q): DPP within 16, shuffles only for 16/32
            float xq = (l < DM) ? qreg : 0.f;
            float q1s = row16_sum(xq);
            float q2s = row16_sum(xq*xq);
            q1s += __shfl_xor(q1s, 16); q2s += __shfl_xor(q2s, 16);
            q1s += __shfl_xor(q1s, 32); q2s += __shfl_xor(q2s, 32);
            float mu = q1s * (1.f/48.f);
            float rs = rsqrtf(q2s * (1.f/48.f) - mu*mu + 1e-5f);
            if (l < DM) w_hilo(qnh, qnl, l, (xq - mu)*rs*s_lnqg[jl] + s_lnqb[jl]);
            // Q = MFMA(wq, qn hi+lo); bias via qn[48]=1, wq col48=bq
            s16x8 Bq0h = *(const s16x8*)&qnh[g8];
            s16x8 Bq1h = *(const s16x8*)&qnh[32 + g8];
            s16x8 Bq0l = *(const s16x8*)&qnl[g8];
            s16x8 Bq1l = *(const s16x8*)&qnl[32 + g8];
            __builtin_amdgcn_s_setprio(1);
            #pragma unroll
            for (int mt = 0; mt < 3; ++mt) {
                const u16* ar = &s_wq[(mt*16 + lm)*WQ_ST];
                s16x8 A0 = *(const s16x8*)&ar[g8];
                s16x8 A1 = (g8 < 24) ? *(const s16x8*)&ar[32 + g8] : *(const s16x8*)zblk;
                f32x4 acc = {0.f, 0.f, 0.f, 0.f};
                acc = MFMA(A0, Bq0h, acc);
                acc = MFMA(A1, Bq1h, acc);
                acc = MFMA(A0, Bq0l, acc);
                acc = MFMA(A1, Bq1l, acc);
                if (lm == 0) *(f32x4*)&Qv[mt*16 + g*4] = acc;
            }
            __builtin_amdgcn_s_setprio(0);
            // scores + softmax, no max-subtraction (r17-proven); DPP + 1 shuffle
            float dt = 0.f;
            #pragma unroll
            for (int d4 = 0; d4 < 6; ++d4) {
                float4 q4 = *(const float4*)&Qv[sh*HDm + d4*4];
                uint2 ku = *(const uint2*)&kv[sn*KV_ST + sh*HDm + d4*4];
                dt = fmaf(q4.x, bu2f_lo(ku.x), dt);
                dt = fmaf(q4.y, bu2f_hi(ku.x), dt);
                dt = fmaf(q4.z, bu2f_lo(ku.y), dt);
                dt = fmaf(q4.w, bu2f_hi(ku.y), dt);
            }
            float ex = sact ? __expf(dt * 0.20412414523193154f) : 0.f;
            float se = row16_sum(ex);
            se += __shfl_xor(se, 16);
            aw[l] = ex / se;    // lanes snn>=21 get exactly 0
            // attn via V^T: b64 reads at stride 28 u16; pad cols * aw=0
            float at = 0.f;
            #pragma unroll
            for (int b = 0; b < 6; ++b) {
                uint2 vv = *(const uint2*)&un[jl*VT_ST + b*4];
                const float* ap = &aw[h2*32 + b*4];
                float2 a0 = *(const float2*)(ap + 0);
                float2 a1 = *(const float2*)(ap + 2);
                at = fmaf(a0.x, bu2f_lo(vv.x), at);
                at = fmaf(a0.y, bu2f_hi(vv.x), at);
                at = fmaf(a1.x, bu2f_lo(vv.y), at);
                at = fmaf(a1.y, bu2f_hi(vv.y), at);
            }
            if (l < DM) w_hilo(xch, xcl, l, at);
            // GRU: vg1[0:96]=r,z pre-act; vg1[96:144]=i_n; h_n separate (vg2)
            s16x8 Bc0h = *(const s16x8*)&xch[g8];
            s16x8 Bc1h = *(const s16x8*)&xch[32 + g8];
            s16x8 Bc2h = *(const s16x8*)&xch[64 + g8];
            s16x8 Bc0l = *(const s16x8*)&xcl[g8];
            s16x8 Bc1l = *(const s16x8*)&xcl[32 + g8];
            s16x8 Bc2l = *(const s16x8*)&xcl[64 + g8];
            __builtin_amdgcn_s_setprio(1);
            #pragma unroll 3
            for (int mt = 0; mt < 9; ++mt) {
                const u16* ar = &s_wcat[(mt*16 + lm)*WC_ST];
                s16x8 A0 = *(const s16x8*)&ar[g8];
                s16x8 A1 = *(const s16x8*)&ar[32 + g8];
                f32x4 acc = {0.f, 0.f, 0.f, 0.f};
                acc = MFMA(A0, Bc0h, acc);
                acc = MFMA(A1, Bc1h, acc);
                acc = MFMA(A0, Bc0l, acc);
                acc = MFMA(A1, Bc1l, acc);
                if (mt < 6) {
                    s16x8 A2 = *(const s16x8*)&ar[64 + g8];
                    acc = MFMA(A2, Bc2h, acc);
                    acc = MFMA(A2, Bc2l, acc);
                }
                if (lm == 0) *(f32x4*)&vg1[mt*16 + g*4] = acc;
            }
            s16x8 Bh0h = *(const s16x8*)&xch[48 + g8];
            s16x8 Bh1h = *(const s16x8*)&xch[80 + g8];  // g2: xch[96]=1 bias, g3: zeros
            s16x8 Bh0l = *(const s16x8*)&xcl[48 + g8];
            s16x8 Bh1l = *(const s16x8*)&xcl[80 + g8];
            #pragma unroll
            for (int mt = 0; mt < 3; ++mt) {
                const u16* ar = &s_whn[(mt*16 + lm)*WHN_ST];
                s16x8 A0 = *(const s16x8*)&ar[g8];
                s16x8 A1 = (g8 < 24) ? *(const s16x8*)&ar[32 + g8] : *(const s16x8*)zblk;
                f32x4 acc = {0.f, 0.f, 0.f, 0.f};
                acc = MFMA(A0, Bh0h, acc);
                acc = MFMA(A1, Bh1h, acc);
                acc = MFMA(A0, Bh0l, acc);
                acc = MFMA(A1, Bh1l, acc);
                if (lm == 0) *(f32x4*)&vg2[mt*16 + g*4] = acc;
            }
            __builtin_amdgcn_s_setprio(0);
            float yr = vg1[jl]      + s_bg[jl];
            float yz = vg1[48 + jl] + s_bg[48 + jl];
            float yn = vg1[96 + jl] + s_bg[96 + jl];
            float hn = vg2[jl];
            float r = 1.f / (1.f + __expf(-yr));
            float z = 1.f / (1.f + __expf(-yz));
            float nn = ftanh(yn + r*hn);
            qreg = (1.f - z)*nn + z*qreg;
            if (l < DM) w_hilo(xch, xcl, 48 + l, qreg);
        }

        // ---- outputs ----
        if (l < NS)
            outp[(size_t)M*DM + (size_t)m*NS + l] = 0.5f*(aw[l] + aw[32 + l]);
        float f = qreg;
        float ratio = fminf(fabsf(f) / s_sig[jl], 15.f);
        float rp = __powf(ratio, pexp);
        f = f / __powf(1.f + rp, pinv);
        if (l < DM) Qv[l] = f;      // Qv reused as tail vx (Q dead)
        float4 a4 = {0,0,0,0};
        #pragma unroll
        for (int d4 = 0; d4 < 12; ++d4) {
            uint2 rw = *(const uint2*)&s_p1[jl*P_ST + d4*4];
            float4 x4 = *(const float4*)&Qv[d4*4];
            a4.x = fmaf(bu2f_lo(rw.x), x4.x, a4.x);
            a4.y = fmaf(bu2f_hi(rw.x), x4.y, a4.y);
            a4.z = fmaf(bu2f_lo(rw.y), x4.z, a4.z);
            a4.w = fmaf(bu2f_hi(rw.y), x4.w, a4.w);
        }
        float h1 = fmaxf(0.f, s_p1b[jl] + (a4.x + a4.y) + (a4.z + a4.w));
        if (l < DM) Qv[l] = h1;
        float4 c4 = {0,0,0,0};
        #pragma unroll
        for (int d4 = 0; d4 < 12; ++d4) {
            uint2 rw = *(const uint2*)&s_p2[jl*P_ST + d4*4];
            float4 x4 = *(const float4*)&Qv[d4*4];
            c4.x = fmaf(bu2f_lo(rw.x), x4.x, c4.x);
            c4.y = fmaf(bu2f_hi(rw.x), x4.y, c4.y);
            c4.z = fmaf(bu2f_lo(rw.y), x4.z, c4.z);
            c4.w = fmaf(bu2f_hi(rw.y), x4.w, c4.w);
        }
        if (l < DM) outp[(size_t)m*DM + l] = s_p2b[jl] + (c4.x + c4.y) + (c4.z + c4.w);
    }
}

extern "C" void kernel_launch(void* const* d_in, const int* in_sizes, int n_in,
                              void* d_out, int out_size, void* d_ws, size_t ws_size,
                              hipStream_t stream) {
    const float* slot = (const float*)d_in[0];
    const float* fq   = (const float*)d_in[1];
    const float* ipw  = (const float*)d_in[2];
    const float* ipb  = (const float*)d_in[3];
    const float* opw  = (const float*)d_in[4];
    const float* opb  = (const float*)d_in[5];
    const float* lnqg = (const float*)d_in[6];
    const float* lnqb = (const float*)d_in[7];
    const float* lnkg = (const float*)d_in[8];
    const float* lnkb = (const float*)d_in[9];
    const float* wih  = (const float*)d_in[10];
    const float* whh  = (const float*)d_in[11];
    const float* bihp = (const float*)d_in[12];
    const float* bhhp = (const float*)d_in[13];
    const float* sigr = (const float*)d_in[14];
    const float* praw = (const float*)d_in[15];
    const float* p1w  = (const float*)d_in[16];
    const float* p1b  = (const float*)d_in[17];
    const float* p2w  = (const float*)d_in[18];
    const float* p2b  = (const float*)d_in[19];
    const int M = in_sizes[0] / (NS*DM);   // 65536
    fusion_kernel<<<dim3(256), dim3(NTHR), 0, stream>>>(
        slot, fq, ipw, ipb, opw, opb, lnqg, lnqb, lnkg, lnkb,
        wih, whh, bihp, bhhp, sigr, praw, p1w, p1b, p2w, p2b,
        (float*)d_out, M);
}

// Round 19
// 446.319 us; speedup vs baseline: 1.4218x; 1.0100x over previous
//
#include <hip/hip_runtime.h>
#include <hip/hip_bf16.h>

#define DM 48
#define NS 21
#define HDm 24
#define ITERS 3
#define NWAVE 12   // 768 thr = 12 waves = 3/SIMD: proven no-spill point (84 VGPR cap)
#define NTHR (NWAVE*64)

#define KV_ST 56   // kvn/K row stride (u16); col48 = 1.0 (bias one), 49-55 = 0
#define VT_ST 28   // V^T row stride (u16)
#define UN_SZ 1344 // max(NS*KV_ST=1176, 48*VT_ST=1344)
#define WKV_ST 56
#define WQ_ST 56
#define WHN_ST 56
#define WC_ST 104
#define P_ST 52

typedef short s16x8 __attribute__((ext_vector_type(8)));
typedef float f32x4 __attribute__((ext_vector_type(4)));
typedef unsigned short u16;

// RNE (setup only)
__device__ __forceinline__ u16 f2bu(float f) {
    __hip_bfloat16 h = __float2bfloat16(f);
    return *reinterpret_cast<u16*>(&h);
}
// hot-loop: round-half-away bf16 (2-3 ops; == RNE except exact ties, 1 ulp)
__device__ __forceinline__ u16 f2bu_fast(float f) {
    return (u16)((__float_as_uint(f) + 0x8000u) >> 16);
}
__device__ __forceinline__ float bu2f_lo(unsigned u){ return __uint_as_float(u<<16); }
__device__ __forceinline__ float bu2f_hi(unsigned u){ return __uint_as_float(u & 0xffff0000u); }
// hi/lo split: hi = TRUNCATION (residual plane makes hi rounding irrelevant);
// lo = x - trunc16(x) is EXACT (Sterbenz: operands within 2^-8 relative), then RTNA.
__device__ __forceinline__ void w_hilo(u16* hi, u16* lo, int idx, float x) {
    unsigned b = __float_as_uint(x);
    hi[idx] = (u16)(b >> 16);
    float r = x - __uint_as_float(b & 0xffff0000u);
    lo[idx] = f2bu_fast(r);
}
// overflow-free fast tanh
__device__ __forceinline__ float ftanh(float x) {
    float t = __expf(-2.0f * fabsf(x));
    float r = (1.0f - t) / (1.0f + t);
    return copysignf(r, x);
}
// DPP 16-lane reduce (r7-proven sequence)
template<int C>
__device__ __forceinline__ float dppf(float x) {
    return __builtin_bit_cast(float,
        __builtin_amdgcn_update_dpp(0, __builtin_bit_cast(int, x), C, 0xF, 0xF, true));
}
__device__ __forceinline__ float row16_sum(float x) {
    x += dppf<0xB1>(x); x += dppf<0x4E>(x); x += dppf<0x141>(x); x += dppf<0x140>(x);
    return x;
}
#define MFMA(a,b,c) __builtin_amdgcn_mfma_f32_16x16x32_bf16(a,b,c,0,0,0)

__global__ __launch_bounds__(NTHR, 3) void fusion_kernel(
    const float* __restrict__ slot, const float* __restrict__ fq,
    const float* __restrict__ ipw,  const float* __restrict__ ipb,
    const float* __restrict__ opw,  const float* __restrict__ opb,
    const float* __restrict__ lnqg, const float* __restrict__ lnqb,
    const float* __restrict__ lnkg, const float* __restrict__ lnkb,
    const float* __restrict__ wih,  const float* __restrict__ whh,
    const float* __restrict__ bih,  const float* __restrict__ bhh,
    const float* __restrict__ sigr, const float* __restrict__ praw,
    const float* __restrict__ p1w,  const float* __restrict__ p1b,
    const float* __restrict__ p2w,  const float* __restrict__ p2b,
    float* __restrict__ outp, const int M)
{
    // ---- block-wide weights (r18 layout) ----
    __shared__ __align__(16) u16 s_wkv[96*WKV_ST];
    __shared__ __align__(16) u16 s_wq [48*WQ_ST];
    __shared__ __align__(16) u16 s_whn[48*WHN_ST];
    __shared__ __align__(16) u16 s_wcat[144*WC_ST];
    __shared__ __align__(16) u16 s_p1[48*P_ST];
    __shared__ __align__(16) u16 s_p2[48*P_ST];
    __shared__ __align__(16) u16 zblk[8];
    __shared__ float s_bg[144];
    __shared__ __align__(16) float s_lnqg[48], s_lnqb[48];
    __shared__ __align__(16) float s_lnkg[48], s_lnkb[48];
    __shared__ float s_sig[48], s_p1b[48], s_p2b[48], s_fq[48];
    __shared__ float s_pp;
    // ---- per-wave scratch ----
    __shared__ __align__(16) u16   s_kv [NWAVE][NS*KV_ST];  // kvn hi, then K overlay
    __shared__ __align__(16) u16   s_un [NWAVE][UN_SZ];     // kvn lo plane, then V^T
    __shared__ __align__(16) u16   s_qnh[NWAVE][64];
    __shared__ __align__(16) u16   s_qnl[NWAVE][64];
    __shared__ __align__(16) u16   s_xch[NWAVE][112];
    __shared__ __align__(16) u16   s_xcl[NWAVE][112];
    __shared__ __align__(16) float s_Qv [NWAVE][48];
    __shared__ __align__(16) float s_aw [NWAVE][64];
    __shared__ __align__(16) float s_g1 [NWAVE][144];
    __shared__ __align__(16) float s_g2 [NWAVE][48];

    const int tid = threadIdx.x;
    for (int i = tid; i < 48*WQ_ST; i += NTHR) {
        int r = i / WQ_ST, c = i - r*WQ_ST;
        s_wq[i] = f2bu(c < 48 ? ipw[r*48+c] : (c == 48 ? ipb[r] : 0.f));
    }
    for (int i = tid; i < 96*WKV_ST; i += NTHR) {
        int r = i / WKV_ST, c = i - r*WKV_ST;
        s_wkv[i] = f2bu(c < 48 ? ipw[(48+r)*48+c] : (c == 48 ? ipb[48+r] : 0.f));
    }
    for (int i = tid; i < 48*WHN_ST; i += NTHR) {
        int r = i / WHN_ST, c = i - r*WHN_ST;
        s_whn[i] = f2bu(c < 48 ? whh[(96+r)*48+c] : (c == 48 ? bhh[96+r] : 0.f));
    }
    for (int i = tid; i < 144*WC_ST; i += NTHR) {
        int r = i / WC_ST, c = i - r*WC_ST;
        float v = 0.f;
        if (c < 48) { float a = 0.f;
            for (int t = 0; t < 48; ++t) a = fmaf(wih[r*48+t], opw[t*48+c], a);
            v = a;
        } else if (c < 96 && r < 96) v = whh[r*48 + (c-48)];
        s_wcat[i] = f2bu(v);
    }
    for (int i = tid; i < 48*P_ST; i += NTHR) {
        int r = i / P_ST, c = i - r*P_ST;
        s_p1[i] = f2bu(c < 48 ? p1w[r*48+c] : 0.f);
        s_p2[i] = f2bu(c < 48 ? p2w[r*48+c] : 0.f);
    }
    if (tid < 144) {
        float a = bih[tid] + (tid < 96 ? bhh[tid] : 0.f);
        for (int t = 0; t < 48; ++t) a = fmaf(wih[tid*48+t], opb[t], a);
        s_bg[tid] = a;
    }
    if (tid < 48) {
        s_lnqg[tid] = lnqg[tid]; s_lnqb[tid] = lnqb[tid];
        s_lnkg[tid] = lnkg[tid]; s_lnkb[tid] = lnkb[tid];
        s_sig[tid] = log1pf(__expf(sigr[tid])) + 0.01f;
        s_p1b[tid] = p1b[tid]; s_p2b[tid] = p2b[tid];
        s_fq[tid] = fq[tid];
    }
    if (tid < 8) zblk[tid] = 0;
    if (tid == 0) s_pp = 1.5f + log1pf(__expf(praw[0]));
    __syncthreads();

    const int w = tid >> 6, l = tid & 63;
    const int jl = (l < DM) ? l : 0;
    const int g = l >> 4, u = l & 15, lm = l & 15, g8 = (l >> 4)*8;
    u16* __restrict__ kv = s_kv[w];
    u16* un = s_un[w];       // UNION: kvn-lo plane AND V^T; single pointer, NO restrict
    u16* __restrict__ qnh = s_qnh[w];
    u16* __restrict__ qnl = s_qnl[w];
    u16* __restrict__ xch = s_xch[w];
    u16* __restrict__ xcl = s_xcl[w];
    float* __restrict__ Qv = s_Qv[w];
    float* __restrict__ aw = s_aw[w];
    float* __restrict__ vg1 = s_g1[w];
    float* __restrict__ vg2 = s_g2[w];

    // one-time per-wave inits: whole union buffer finite (NaN guard), kv bias col
    for (int e = l; e < UN_SZ; e += 64) un[e] = 0;
    for (int e = l; e < NS*8; e += 64) {
        int s = e >> 3, c = e & 7;
        kv[s*KV_ST + 48 + c] = (c == 0) ? (u16)0x3F80 : (u16)0;
    }
    if (l >= 48) { qnh[l] = (l == 48) ? (u16)0x3F80 : (u16)0; qnl[l] = 0; }
    if (l < 16)  { xch[96 + l] = (l == 0) ? (u16)0x3F80 : (u16)0; xcl[96 + l] = 0; }

    const float pexp = s_pp, pinv = 1.0f / s_pp;
    const int h2 = (jl >= HDm) ? 1 : 0;
    const int sh = l >> 5, snn = l & 31;
    const bool sact = snn < NS;
    const int sn = sact ? snn : 0;

    for (int m = blockIdx.x*NWAVE + w; m < M; m += gridDim.x*NWAVE) {
        const float* __restrict__ kvp = slot + (size_t)m * (NS*DM);

        // ---- LN(kv) -> kv hi + un lo planes (cols 0-47), hoisted; DPP reduce ----
        #pragma unroll
        for (int i = 0; i < 6; ++i) {
            int n = i*4 + g;
            bool act = (n < NS);
            int nc = act ? n : 0;
            float x0 = kvp[nc*DM + u], x1 = kvp[nc*DM + 16 + u], x2 = kvp[nc*DM + 32 + u];
            float s1 = row16_sum(x0 + x1 + x2);
            float s2 = row16_sum(x0*x0 + x1*x1 + x2*x2);
            float mu = s1 * (1.f/48.f);
            float rs = rsqrtf(s2 * (1.f/48.f) - mu*mu + 1e-5f);
            if (act) {
                w_hilo(kv, un, nc*KV_ST + u,      (x0 - mu)*rs*s_lnkg[u]    + s_lnkb[u]);
                w_hilo(kv, un, nc*KV_ST + 16 + u, (x1 - mu)*rs*s_lnkg[16+u] + s_lnkb[16+u]);
                w_hilo(kv, un, nc*KV_ST + 32 + u, (x2 - mu)*rs*s_lnkg[32+u] + s_lnkb[32+u]);
            }
        }

        // ---- K,V via MFMA: A=wkv bf16, B=kvn hi+lo (effective fp32) ----
        s16x8 Bh[2][2], Bl[2][2];
        #pragma unroll
        for (int nt = 0; nt < 2; ++nt) {
            int sl = lm + nt*16; if (sl > NS-1) sl = NS-1;   // clamped: D discarded
            Bh[nt][0] = *(const s16x8*)&kv[sl*KV_ST + g8];
            Bh[nt][1] = (g8 < 24) ? *(const s16x8*)&kv[sl*KV_ST + 32 + g8]
                                  : *(const s16x8*)zblk;
            Bl[nt][0] = *(const s16x8*)&un[sl*KV_ST + g8];
            Bl[nt][1] = (g8 < 16) ? *(const s16x8*)&un[sl*KV_ST + 32 + g8]
                                  : *(const s16x8*)zblk;   // lo of bias cols = 0
        }
        __builtin_amdgcn_s_setprio(1);   // MFMA-heavy phase (T5)
        #pragma unroll
        for (int mt = 0; mt < 6; ++mt) {
            const u16* ar = &s_wkv[(mt*16 + lm)*WKV_ST];
            s16x8 A0 = *(const s16x8*)&ar[g8];
            s16x8 A1 = (g8 < 24) ? *(const s16x8*)&ar[32 + g8] : *(const s16x8*)zblk;
            #pragma unroll
            for (int nt = 0; nt < 2; ++nt) {
                f32x4 acc = {0.f, 0.f, 0.f, 0.f};
                acc = MFMA(A0, Bh[nt][0], acc);
                acc = MFMA(A1, Bh[nt][1], acc);
                acc = MFMA(A0, Bl[nt][0], acc);
                acc = MFMA(A1, Bl[nt][1], acc);
                int slotn = lm + nt*16;
                if (slotn < NS) {
                    if (mt < 3) {        // K -> overlay kv cols 0-47 (B reads done)
                        uint2 pk;
                        pk.x = (unsigned)f2bu_fast(acc[0]) | ((unsigned)f2bu_fast(acc[1]) << 16);
                        pk.y = (unsigned)f2bu_fast(acc[2]) | ((unsigned)f2bu_fast(acc[3]) << 16);
                        *(uint2*)&kv[slotn*KV_ST + mt*16 + g*4] = pk;
                    } else {             // V -> transposed store into union buffer
                        int ch = (mt-3)*16 + g*4;
                        un[(ch+0)*VT_ST + slotn] = f2bu_fast(acc[0]);
                        un[(ch+1)*VT_ST + slotn] = f2bu_fast(acc[1]);
                        un[(ch+2)*VT_ST + slotn] = f2bu_fast(acc[2]);
                        un[(ch+3)*VT_ST + slotn] = f2bu_fast(acc[3]);
                    }
                }
            }
        }
        __builtin_amdgcn_s_setprio(0);

        // ---- 3 GRU-attention iterations ----
        float qreg = s_fq[jl];
        if (l < DM) w_hilo(xch, xcl, 48 + l, qreg);
        #pragma unroll 1
        for (int it = 0; it < ITERS; ++it) {
            // LN(q): DPP within 16, shuffles for 16/32
            float xq = (l < DM) ? qreg : 0.f;
            float q1s = row16_sum(xq);
            float q2s = row16_sum(xq*xq);
            q1s += __shfl_xor(q1s, 16); q2s += __shfl_xor(q2s, 16);
            q1s += __shfl_xor(q1s, 32); q2s += __shfl_xor(q2s, 32);
            float mu = q1s * (1.f/48.f);
            float rs = rsqrtf(q2s * (1.f/48.f) - mu*mu + 1e-5f);
            if (l < DM) w_hilo(qnh, qnl, l, (xq - mu)*rs*s_lnqg[jl] + s_lnqb[jl]);
            // Q = MFMA(wq, qn hi+lo); bias via qn[48]=1, wq col48=bq
            s16x8 Bq0h = *(const s16x8*)&qnh[g8];
            s16x8 Bq1h = *(const s16x8*)&qnh[32 + g8];
            s16x8 Bq0l = *(const s16x8*)&qnl[g8];
            s16x8 Bq1l = *(const s16x8*)&qnl[32 + g8];
            __builtin_amdgcn_s_setprio(1);
            #pragma unroll
            for (int mt = 0; mt < 3; ++mt) {
                const u16* ar = &s_wq[(mt*16 + lm)*WQ_ST];
                s16x8 A0 = *(const s16x8*)&ar[g8];
                s16x8 A1 = (g8 < 24) ? *(const s16x8*)&ar[32 + g8] : *(const s16x8*)zblk;
                f32x4 acc = {0.f, 0.f, 0.f, 0.f};
                acc = MFMA(A0, Bq0h, acc);
                acc = MFMA(A1, Bq1h, acc);
                acc = MFMA(A0, Bq0l, acc);
                acc = MFMA(A1, Bq1l, acc);
                if (lm == 0) *(f32x4*)&Qv[mt*16 + g*4] = acc;
            }
            __builtin_amdgcn_s_setprio(0);
            // scores + softmax, no max-subtraction (r17-proven); DPP + 1 shuffle
            float dt = 0.f;
            #pragma unroll
            for (int d4 = 0; d4 < 6; ++d4) {
                float4 q4 = *(const float4*)&Qv[sh*HDm + d4*4];
                uint2 ku = *(const uint2*)&kv[sn*KV_ST + sh*HDm + d4*4];
                dt = fmaf(q4.x, bu2f_lo(ku.x), dt);
                dt = fmaf(q4.y, bu2f_hi(ku.x), dt);
                dt = fmaf(q4.z, bu2f_lo(ku.y), dt);
                dt = fmaf(q4.w, bu2f_hi(ku.y), dt);
            }
            float ex = sact ? __expf(dt * 0.20412414523193154f) : 0.f;
            float se = row16_sum(ex);
            se += __shfl_xor(se, 16);
            aw[l] = ex / se;    // lanes snn>=21 get exactly 0
            // attn via V^T: b64 reads at stride 28 u16; pad cols * aw=0
            float at = 0.f;
            #pragma unroll
            for (int b = 0; b < 6; ++b) {
                uint2 vv = *(const uint2*)&un[jl*VT_ST + b*4];
                const float* ap = &aw[h2*32 + b*4];
                float2 a0 = *(const float2*)(ap + 0);
                float2 a1 = *(const float2*)(ap + 2);
                at = fmaf(a0.x, bu2f_lo(vv.x), at);
                at = fmaf(a0.y, bu2f_hi(vv.x), at);
                at = fmaf(a1.x, bu2f_lo(vv.y), at);
                at = fmaf(a1.y, bu2f_hi(vv.y), at);
            }
            if (l < DM) w_hilo(xch, xcl, l, at);
            // GRU: vg1[0:96]=r,z pre-act; vg1[96:144]=i_n; h_n separate (vg2)
            s16x8 Bc0h = *(const s16x8*)&xch[g8];
            s16x8 Bc1h = *(const s16x8*)&xch[32 + g8];
            s16x8 Bc2h = *(const s16x8*)&xch[64 + g8];
            s16x8 Bc0l = *(const s16x8*)&xcl[g8];
            s16x8 Bc1l = *(const s16x8*)&xcl[32 + g8];
            s16x8 Bc2l = *(const s16x8*)&xcl[64 + g8];
            __builtin_amdgcn_s_setprio(1);
            #pragma unroll 3
            for (int mt = 0; mt < 9; ++mt) {
                const u16* ar = &s_wcat[(mt*16 + lm)*WC_ST];
                s16x8 A0 = *(const s16x8*)&ar[g8];
                s16x8 A1 = *(const s16x8*)&ar[32 + g8];
                f32x4 acc = {0.f, 0.f, 0.f, 0.f};
                acc = MFMA(A0, Bc0h, acc);
                acc = MFMA(A1, Bc1h, acc);
                acc = MFMA(A0, Bc0l, acc);
                acc = MFMA(A1, Bc1l, acc);
                if (mt < 6) {
                    s16x8 A2 = *(const s16x8*)&ar[64 + g8];
                    acc = MFMA(A2, Bc2h, acc);
                    acc = MFMA(A2, Bc2l, acc);
                }
                if (lm == 0) *(f32x4*)&vg1[mt*16 + g*4] = acc;
            }
            s16x8 Bh0h = *(const s16x8*)&xch[48 + g8];
            s16x8 Bh1h = *(const s16x8*)&xch[80 + g8];  // g2: xch[96]=1 bias, g3: zeros
            s16x8 Bh0l = *(const s16x8*)&xcl[48 + g8];
            s16x8 Bh1l = *(const s16x8*)&xcl[80 + g8];
            #pragma unroll
            for (int mt = 0; mt < 3; ++mt) {
                const u16* ar = &s_whn[(mt*16 + lm)*WHN_ST];
                s16x8 A0 = *(const s16x8*)&ar[g8];
                s16x8 A1 = (g8 < 24) ? *(const s16x8*)&ar[32 + g8] : *(const s16x8*)zblk;
                f32x4 acc = {0.f, 0.f, 0.f, 0.f};
                acc = MFMA(A0, Bh0h, acc);
                acc = MFMA(A1, Bh1h, acc);
                acc = MFMA(A0, Bh0l, acc);
                acc = MFMA(A1, Bh1l, acc);
                if (lm == 0) *(f32x4*)&vg2[mt*16 + g*4] = acc;
            }
            __builtin_amdgcn_s_setprio(0);
            float yr = vg1[jl]      + s_bg[jl];
            float yz = vg1[48 + jl] + s_bg[48 + jl];
            float yn = vg1[96 + jl] + s_bg[96 + jl];
            float hn = vg2[jl];
            float r = 1.f / (1.f + __expf(-yr));
            float z = 1.f / (1.f + __expf(-yz));
            float nn = ftanh(yn + r*hn);
            qreg = (1.f - z)*nn + z*qreg;
            if (l < DM) w_hilo(xch, xcl, 48 + l, qreg);
        }

        // ---- outputs ----
        if (l < NS)
            outp[(size_t)M*DM + (size_t)m*NS + l] = 0.5f*(aw[l] + aw[32 + l]);
        float f = qreg;
        float ratio = fminf(fabsf(f) / s_sig[jl], 15.f);
        float rp = __powf(ratio, pexp);
        f = f / __powf(1.f + rp, pinv);
        if (l < DM) Qv[l] = f;      // Qv reused as tail vx (Q dead)
        float4 a4 = {0,0,0,0};
        #pragma unroll
        for (int d4 = 0; d4 < 12; ++d4) {
            uint2 rw = *(const uint2*)&s_p1[jl*P_ST + d4*4];
            float4 x4 = *(const float4*)&Qv[d4*4];
            a4.x = fmaf(bu2f_lo(rw.x), x4.x, a4.x);
            a4.y = fmaf(bu2f_hi(rw.x), x4.y, a4.y);
            a4.z = fmaf(bu2f_lo(rw.y), x4.z, a4.z);
            a4.w = fmaf(bu2f_hi(rw.y), x4.w, a4.w);
        }
        float h1 = fmaxf(0.f, s_p1b[jl] + (a4.x + a4.y) + (a4.z + a4.w));
        if (l < DM) Qv[l] = h1;
        float4 c4 = {0,0,0,0};
        #pragma unroll
        for (int d4 = 0; d4 < 12; ++d4) {
            uint2 rw = *(const uint2*)&s_p2[jl*P_ST + d4*4];
            float4 x4 = *(const float4*)&Qv[d4*4];
            c4.x = fmaf(bu2f_lo(rw.x), x4.x, c4.x);
            c4.y = fmaf(bu2f_hi(rw.x), x4.y, c4.y);
            c4.z = fmaf(bu2f_lo(rw.y), x4.z, c4.z);
            c4.w = fmaf(bu2f_hi(rw.y), x4.w, c4.w);
        }
        if (l < DM) outp[(size_t)m*DM + l] = s_p2b[jl] + (c4.x + c4.y) + (c4.z + c4.w);
    }
}

extern "C" void kernel_launch(void* const* d_in, const int* in_sizes, int n_in,
                              void* d_out, int out_size, void* d_ws, size_t ws_size,
                              hipStream_t stream) {
    const float* slot = (const float*)d_in[0];
    const float* fq   = (const float*)d_in[1];
    const float* ipw  = (const float*)d_in[2];
    const float* ipb  = (const float*)d_in[3];
    const float* opw  = (const float*)d_in[4];
    const float* opb  = (const float*)d_in[5];
    const float* lnqg = (const float*)d_in[6];
    const float* lnqb = (const float*)d_in[7];
    const float* lnkg = (const float*)d_in[8];
    const float* lnkb = (const float*)d_in[9];
    const float* wih  = (const float*)d_in[10];
    const float* whh  = (const float*)d_in[11];
    const float* bihp = (const float*)d_in[12];
    const float* bhhp = (const float*)d_in[13];
    const float* sigr = (const float*)d_in[14];
    const float* praw = (const float*)d_in[15];
    const float* p1w  = (const float*)d_in[16];
    const float* p1b  = (const float*)d_in[17];
    const float* p2w  = (const float*)d_in[18];
    const float* p2b  = (const float*)d_in[19];
    const int M = in_sizes[0] / (NS*DM);   // 65536
    fusion_kernel<<<dim3(256), dim3(NTHR), 0, stream>>>(
        slot, fq, ipw, ipb, opw, opb, lnqg, lnqb, lnkg, lnkb,
        wih, whh, bihp, bhhp, sigr, praw, p1w, p1b, p2w, p2b,
        (float*)d_out, M);
}